// Round 11
// baseline (490.432 us; speedup 1.0000x reference)
//
#include <hip/hip_runtime.h>
#include <hip/hip_bf16.h>
#include <cstddef>

#define L_SEQ   2048
#define NBATCH  2
#define NROWS   (NBATCH * L_SEQ)   /* 4096 */
#define NSTATE  16
#define CH      64
#define NCHUNK  (L_SEQ / CH)       /* 32 */

typedef __bf16 bf16x8 __attribute__((ext_vector_type(8)));
typedef float  f32x4  __attribute__((ext_vector_type(4)));
typedef unsigned short u16x4 __attribute__((ext_vector_type(4)));

static __device__ __forceinline__ unsigned short f2bf(float f) {
  unsigned int x = __builtin_bit_cast(unsigned int, f);
  x += 0x7fffu + ((x >> 16) & 1u);          // RNE
  return (unsigned short)(x >> 16);
}
static __device__ __forceinline__ float bf2f(unsigned short u) {
  return __builtin_bit_cast(float, ((unsigned int)u) << 16);
}

// async global->LDS, 16B per lane; LDS dest = wave-uniform base + lane*16
#define GLDS(g, l) __builtin_amdgcn_global_load_lds( \
    (const __attribute__((address_space(1))) void*)(g), \
    (__attribute__((address_space(3))) void*)(l), 16, 0, 0)

#define DRAIN_VM() asm volatile("s_waitcnt vmcnt(0)" ::: "memory")

// ---------------------------------------------------------------- f32 -> bf16 (generic, for xdbl)
__global__ __launch_bounds__(256) void cvt_bf16_kernel(
    const float* __restrict__ in, unsigned short* __restrict__ out, int n4)
{
  const int i = blockIdx.x * 256 + threadIdx.x;
  if (i < n4) {
    const float4 v = reinterpret_cast<const float4*>(in)[i];
    u16x4 o;
    o[0] = f2bf(v.x); o[1] = f2bf(v.y); o[2] = f2bf(v.z); o[3] = f2bf(v.w);
    reinterpret_cast<u16x4*>(out)[i] = o;
  }
}

// ---------------------------------------------------------------- all weights -> bf16, one launch
__global__ __launch_bounds__(256) void cvt_all_kernel(
    const float* __restrict__ ipw, const float* __restrict__ xpw,
    const float* __restrict__ dtw, const float* __restrict__ opw,
    const float* __restrict__ w1,  const float* __restrict__ w2,
    const float* __restrict__ few,
    unsigned short* __restrict__ o_ipw, unsigned short* __restrict__ o_xpw,
    unsigned short* __restrict__ o_dtw, unsigned short* __restrict__ o_opw,
    unsigned short* __restrict__ o_w1,  unsigned short* __restrict__ o_w2,
    unsigned short* __restrict__ o_few)
{
  int i = blockIdx.x * 256 + threadIdx.x;
  const float* src; unsigned short* dst;
  if (i < 524288)                 { src = ipw; dst = o_ipw; }
  else if ((i -= 524288) < 24576) { src = xpw; dst = o_xpw; }
  else if ((i -= 24576) < 16384)  { src = dtw; dst = o_dtw; }
  else if ((i -= 16384) < 262144) { src = opw; dst = o_opw; }
  else if ((i -= 262144) < 1048576){ src = w1; dst = o_w1; }
  else if ((i -= 1048576) < 1048576){ src = w2; dst = o_w2; }
  else if ((i -= 1048576) < 262144){ src = few; dst = o_few; }
  else return;
  const float4 v = reinterpret_cast<const float4*>(src)[i];
  u16x4 o;
  o[0] = f2bf(v.x); o[1] = f2bf(v.y); o[2] = f2bf(v.z); o[3] = f2bf(v.w);
  reinterpret_cast<u16x4*>(dst)[i] = o;
}

// ---------------------------------------------------------------- LayerNorm
__global__ __launch_bounds__(256) void ln_kernel(
    const float* __restrict__ in, const float* __restrict__ g,
    const float* __restrict__ bta, const float* __restrict__ res,
    float* __restrict__ out, unsigned short* __restrict__ outb)
{
  const int row = blockIdx.x;
  const int tid = threadIdx.x;
  __shared__ float sm[8];
  const float4 v = reinterpret_cast<const float4*>(in + (size_t)row * 1024)[tid];
  float s = v.x + v.y + v.z + v.w;
#pragma unroll
  for (int o = 32; o > 0; o >>= 1) s += __shfl_down(s, o, 64);
  if ((tid & 63) == 0) sm[tid >> 6] = s;
  __syncthreads();
  const float mean = (sm[0] + sm[1] + sm[2] + sm[3]) * (1.f / 1024.f);
  const float dx = v.x - mean, dy = v.y - mean, dz = v.z - mean, dw = v.w - mean;
  float q = dx * dx + dy * dy + dz * dz + dw * dw;
#pragma unroll
  for (int o = 32; o > 0; o >>= 1) q += __shfl_down(q, o, 64);
  __syncthreads();
  if ((tid & 63) == 0) sm[tid >> 6] = q;
  __syncthreads();
  const float var = (sm[0] + sm[1] + sm[2] + sm[3]) * (1.f / 1024.f);
  const float rstd = rsqrtf(var + 1e-5f);
  const float4 gv = reinterpret_cast<const float4*>(g)[tid];
  const float4 bv = reinterpret_cast<const float4*>(bta)[tid];
  float4 o4;
  o4.x = dx * rstd * gv.x + bv.x;
  o4.y = dy * rstd * gv.y + bv.y;
  o4.z = dz * rstd * gv.z + bv.z;
  o4.w = dw * rstd * gv.w + bv.w;
  if (outb) {
    u16x4 ob;
    ob[0] = f2bf(o4.x); ob[1] = f2bf(o4.y); ob[2] = f2bf(o4.z); ob[3] = f2bf(o4.w);
    reinterpret_cast<u16x4*>(outb + (size_t)row * 1024)[tid] = ob;
  } else {
    if (res) {
      const float4 rv = reinterpret_cast<const float4*>(res + (size_t)row * 1024)[tid];
      o4.x += rv.x; o4.y += rv.y; o4.z += rv.z; o4.w += rv.w;
    }
    reinterpret_cast<float4*>(out + (size_t)row * 1024)[tid] = o4;
  }
}

// ---------------------------------------------------------------- bf16 GEMM, 2-phase pipelined (round-8 proven)
// C[M][N] = act(A[M][K] @ B[N][K]^T + bias) + res ; tiles 128x128, BK=32
// act: 0 none, 1 softplus, 2 leaky(0.01). outbf: write bf16.
// grid.x = (M/128)*gy with bijective XCD-chunked swizzle; gy = N/128.
// grid.y = split-K chunks; K = chunk length. split!=0: f32 atomicAdd epilogue
// (no bias/act/res; caller pre-seeds C).
__global__ __launch_bounds__(256) void gemm_bf16_kernel(
    const unsigned short* __restrict__ A, int lda,
    const unsigned short* __restrict__ B, int ldb,
    void* __restrict__ Cv, int ldc,
    const float* __restrict__ bias, const float* __restrict__ res,
    int K, int act, int outbf, int gy, int split)
{
  __shared__ unsigned short As[2][128 * 32];
  __shared__ unsigned short Bs[2][128 * 32];
  const int t = threadIdx.x;
  const int w = t >> 6, l = t & 63;

  // XCD-chunked bijective swizzle (gridDim.x divisible by 8)
  const int q = gridDim.x >> 3;
  const int nid = (blockIdx.x & 7) * q + (blockIdx.x >> 3);
  const int bm = (nid / gy) * 128;
  const int bn = (nid % gy) * 128;
  const int koff = blockIdx.y * K;   // split-K chunk offset

  const int wr = (w >> 1) * 64, wc = (w & 1) * 64;
  f32x4 acc[4][4] = {};

  const int srow = t >> 2;          // 0..63
  const int sk = (t & 3) * 8;
  const unsigned short* gA0 = A + (size_t)(bm + srow) * lda + koff + sk;
  const unsigned short* gA1 = gA0 + (size_t)64 * lda;
  const unsigned short* gB0 = B + (size_t)(bn + srow) * ldb + koff + sk;
  const unsigned short* gB1 = gB0 + (size_t)64 * ldb;

  const int fr = l & 15;
  const int kb = (l >> 4) * 8;

#define STAGE(buf, k0) do { \
    GLDS(gA0 + (k0), &As[buf][w * 512]); \
    GLDS(gA1 + (k0), &As[buf][2048 + w * 512]); \
    GLDS(gB0 + (k0), &Bs[buf][w * 512]); \
    GLDS(gB1 + (k0), &Bs[buf][2048 + w * 512]); \
  } while (0)

#define COMPUTE(buf) do { \
    bf16x8 af[4], bfr[4]; \
    _Pragma("unroll") \
    for (int i = 0; i < 4; ++i) \
      af[i] = *reinterpret_cast<const bf16x8*>(&As[buf][(wr + i * 16 + fr) * 32 + kb]); \
    _Pragma("unroll") \
    for (int j = 0; j < 4; ++j) \
      bfr[j] = *reinterpret_cast<const bf16x8*>(&Bs[buf][(wc + j * 16 + fr) * 32 + kb]); \
    _Pragma("unroll") \
    for (int i = 0; i < 4; ++i) \
      _Pragma("unroll") \
      for (int j = 0; j < 4; ++j) \
        acc[i][j] = __builtin_amdgcn_mfma_f32_16x16x32_bf16(af[i], bfr[j], acc[i][j], 0, 0, 0); \
  } while (0)

  STAGE(0, 0);
  DRAIN_VM();
  __syncthreads();
  int cur = 0;
  for (int k0 = 32; k0 < K; k0 += 32) {
    __builtin_amdgcn_sched_barrier(0);        // STAGE may not hoist above prev barrier
    STAGE(cur ^ 1, k0);                       // next tile in flight during compute
    __builtin_amdgcn_sched_barrier(0);        // pin issue-early
    COMPUTE(cur);
    DRAIN_VM();                               // explicit LDS-DMA drain before barrier
    __syncthreads();
    cur ^= 1;
  }
  COMPUTE(cur);
#undef STAGE
#undef COMPUTE

  const int crow = (l >> 4) * 4;
  const int ccol = l & 15;
  float* Cf = (float*)Cv;
  unsigned short* Cb = (unsigned short*)Cv;
#pragma unroll
  for (int i = 0; i < 4; ++i) {
#pragma unroll
    for (int j = 0; j < 4; ++j) {
      const int n = bn + wc + j * 16 + ccol;
      const float bv = (!split && bias) ? bias[n] : 0.f;
#pragma unroll
      for (int r = 0; r < 4; ++r) {
        const int m = bm + wr + i * 16 + crow + r;
        if (split) {
          atomicAdd(&Cf[(size_t)m * ldc + n], acc[i][j][r]);
        } else {
          float v = acc[i][j][r] + bv;
          if (act == 1) v = (v > 20.f) ? v : __logf(1.f + __expf(v));
          else if (act == 2) v = (v >= 0.f) ? v : 0.01f * v;
          if (res) v += res[(size_t)m * ldc + n];
          if (outbf) Cb[(size_t)m * ldc + n] = f2bf(v);
          else       Cf[(size_t)m * ldc + n] = v;
        }
      }
    }
  }
}

// ---------------------------------------------------------------- x_proj split-K (N=96), 2-phase (proven)
__global__ __launch_bounds__(256) void xproj_kernel(
    const unsigned short* __restrict__ A, int lda,
    const unsigned short* __restrict__ B, int ldb,
    float* __restrict__ C)
{
  __shared__ unsigned short As[2][128 * 32];
  __shared__ unsigned short Bs[2][96 * 32];
  const int t = threadIdx.x;
  const int w = t >> 6, l = t & 63;
  const int bm = blockIdx.x * 128;
  const int kbase = blockIdx.y * 128;

  f32x4 acc[2][6] = {};

  const int srow = t >> 2;
  const int sk = (t & 3) * 8;
  const unsigned short* gA0 = A + (size_t)(bm + srow) * lda + kbase + sk;
  const unsigned short* gA1 = gA0 + (size_t)64 * lda;
  const unsigned short* gB0 = B + (size_t)srow * ldb + kbase + sk;
  const unsigned short* gB1 = gB0 + (size_t)64 * ldb;

  const int fr = l & 15;
  const int kb = (l >> 4) * 8;

#define STAGEX(buf, k0) do { \
    GLDS(gA0 + (k0), &As[buf][w * 512]); \
    GLDS(gA1 + (k0), &As[buf][2048 + w * 512]); \
    GLDS(gB0 + (k0), &Bs[buf][w * 512]); \
    if (w < 2) GLDS(gB1 + (k0), &Bs[buf][2048 + w * 512]); \
  } while (0)

#define COMPUTEX(buf) do { \
    bf16x8 af[2], bfr[6]; \
    _Pragma("unroll") \
    for (int i = 0; i < 2; ++i) \
      af[i] = *reinterpret_cast<const bf16x8*>(&As[buf][(w * 32 + i * 16 + fr) * 32 + kb]); \
    _Pragma("unroll") \
    for (int j = 0; j < 6; ++j) \
      bfr[j] = *reinterpret_cast<const bf16x8*>(&Bs[buf][(j * 16 + fr) * 32 + kb]); \
    _Pragma("unroll") \
    for (int i = 0; i < 2; ++i) \
      _Pragma("unroll") \
      for (int j = 0; j < 6; ++j) \
        acc[i][j] = __builtin_amdgcn_mfma_f32_16x16x32_bf16(af[i], bfr[j], acc[i][j], 0, 0, 0); \
  } while (0)

  STAGEX(0, 0);
  DRAIN_VM();
  __syncthreads();
  int cur = 0;
  for (int s = 1; s < 4; ++s) {
    __builtin_amdgcn_sched_barrier(0);
    STAGEX(cur ^ 1, s * 32);
    __builtin_amdgcn_sched_barrier(0);
    COMPUTEX(cur);
    DRAIN_VM();
    __syncthreads();
    cur ^= 1;
  }
  COMPUTEX(cur);
#undef STAGEX
#undef COMPUTEX

  const int crow = (l >> 4) * 4;
  const int ccol = l & 15;
#pragma unroll
  for (int i = 0; i < 2; ++i)
#pragma unroll
    for (int j = 0; j < 6; ++j)
#pragma unroll
      for (int r = 0; r < 4; ++r) {
        const int m = bm + w * 32 + i * 16 + crow + r;
        const int n = j * 16 + ccol;
        atomicAdd(&C[(size_t)m * 96 + n], acc[i][j][r]);
      }
}

// ---------------------------------------------------------------- conv(k=2)+SiLU (bf16 xz)
__global__ __launch_bounds__(256) void conv_silu_kernel(
    const unsigned short* __restrict__ xz, const float* __restrict__ cw,
    const float* __restrict__ cb, float* __restrict__ xc,
    unsigned short* __restrict__ xcb)
{
  const int idx = blockIdx.x * 256 + threadIdx.x;   // over 4096*1024
  const int row = idx >> 10;
  const int d = idx & 1023;
  const int l = row & (L_SEQ - 1);
  const float cur = bf2f(xz[(size_t)row * 2048 + d]);
  const float prev = (l == 0) ? 0.f : bf2f(xz[(size_t)(row - 1) * 2048 + d]);
  const float v = prev * cw[d * 2 + 0] + cur * cw[d * 2 + 1] + cb[d];
  const float sv = v / (1.f + __expf(-v));
  xc[idx] = sv;
  xcb[idx] = f2bf(sv);
}

// ---------------------------------------------------------------- scan pass 1
__global__ __launch_bounds__(256) void scan_pass1(
    const float* __restrict__ delta, const float* __restrict__ xc,
    const float* __restrict__ xdbl, const float* __restrict__ A_log,
    float* __restrict__ hfin, float* __restrict__ pcum)
{
  const int tid = threadIdx.x;
  const int db = blockIdx.x & 3;
  const int c = (blockIdx.x >> 2) & (NCHUNK - 1);
  const int b = blockIdx.x >> 7;
  const int d = db * 256 + tid;
  __shared__ float Bsh[CH][16];
  {
    const int lr = tid >> 2, q = tid & 3;
    const float* p = xdbl + ((size_t)(b * L_SEQ + c * CH + lr) * 96) + 64 + q * 4;
    *reinterpret_cast<float4*>(&Bsh[lr][q * 4]) = *reinterpret_cast<const float4*>(p);
  }
  float a[NSTATE];
#pragma unroll
  for (int n = 0; n < NSTATE; ++n) a[n] = -__expf(A_log[d * 16 + n]);
  __syncthreads();
  float h[NSTATE], P[NSTATE];
#pragma unroll
  for (int n = 0; n < NSTATE; ++n) { h[n] = 0.f; P[n] = 1.f; }
  const size_t rowbase = (size_t)(b * L_SEQ + c * CH);
  for (int s = 0; s < CH; ++s) {
    const size_t row = rowbase + s;
    const float dl = delta[row * 1024 + d];
    const float xcv = xc[row * 1024 + d];
#pragma unroll
    for (int n = 0; n < NSTATE; ++n) {
      const float dA = __expf(dl * a[n]);
      h[n] = h[n] * dA + (dl * Bsh[s][n]) * xcv;
      P[n] *= dA;
    }
  }
  const size_t base = ((size_t)((b * NCHUNK + c) * 1024 + d)) * 16;
  float4* hp = reinterpret_cast<float4*>(hfin + base);
  float4* pp = reinterpret_cast<float4*>(pcum + base);
#pragma unroll
  for (int qq = 0; qq < 4; ++qq) {
    hp[qq] = make_float4(h[qq * 4], h[qq * 4 + 1], h[qq * 4 + 2], h[qq * 4 + 3]);
    pp[qq] = make_float4(P[qq * 4], P[qq * 4 + 1], P[qq * 4 + 2], P[qq * 4 + 3]);
  }
}

// ---------------------------------------------------------------- scan pass 2
__global__ __launch_bounds__(256) void scan_pass2(
    const float* __restrict__ hfin, const float* __restrict__ pcum,
    float* __restrict__ hstart)
{
  const int t = blockIdx.x * 256 + threadIdx.x;
  const int b = t >> 14;
  const int dn = t & 16383;
  const size_t base = (size_t)b * NCHUNK * 16384 + dn;
  float h = 0.f;
  for (int c = 0; c < NCHUNK; ++c) {
    const size_t idx = base + (size_t)c * 16384;
    hstart[idx] = h;
    h = pcum[idx] * h + hfin[idx];
  }
}

// ---------------------------------------------------------------- scan pass 3 (bf16 y out, bf16 z in)
__global__ __launch_bounds__(256) void scan_pass3(
    const float* __restrict__ delta, const float* __restrict__ xc,
    const float* __restrict__ xdbl, const float* __restrict__ A_log,
    const float* __restrict__ hstart, const float* __restrict__ Dp,
    const unsigned short* __restrict__ xz, unsigned short* __restrict__ yout)
{
  const int tid = threadIdx.x;
  const int db = blockIdx.x & 3;
  const int c = (blockIdx.x >> 2) & (NCHUNK - 1);
  const int b = blockIdx.x >> 7;
  const int d = db * 256 + tid;
  __shared__ float Bsh[CH][16];
  __shared__ float Csh[CH][16];
  {
    const int lr = tid >> 2, q = tid & 3;
    const float* p = xdbl + ((size_t)(b * L_SEQ + c * CH + lr) * 96);
    *reinterpret_cast<float4*>(&Bsh[lr][q * 4]) = *reinterpret_cast<const float4*>(p + 64 + q * 4);
    *reinterpret_cast<float4*>(&Csh[lr][q * 4]) = *reinterpret_cast<const float4*>(p + 80 + q * 4);
  }
  float a[NSTATE];
#pragma unroll
  for (int n = 0; n < NSTATE; ++n) a[n] = -__expf(A_log[d * 16 + n]);
  float h[NSTATE];
  {
    const size_t base = ((size_t)((b * NCHUNK + c) * 1024 + d)) * 16;
    const float4* hp = reinterpret_cast<const float4*>(hstart + base);
#pragma unroll
    for (int qq = 0; qq < 4; ++qq) {
      const float4 v = hp[qq];
      h[qq * 4] = v.x; h[qq * 4 + 1] = v.y; h[qq * 4 + 2] = v.z; h[qq * 4 + 3] = v.w;
    }
  }
  const float dpv = Dp[d];
  __syncthreads();
  const size_t rowbase = (size_t)(b * L_SEQ + c * CH);
  for (int s = 0; s < CH; ++s) {
    const size_t row = rowbase + s;
    const float dl = delta[row * 1024 + d];
    const float xcv = xc[row * 1024 + d];
    float y = 0.f;
#pragma unroll
    for (int n = 0; n < NSTATE; ++n) {
      const float dA = __expf(dl * a[n]);
      h[n] = h[n] * dA + (dl * Bsh[s][n]) * xcv;
      y += h[n] * Csh[s][n];
    }
    const float z = bf2f(xz[row * 2048 + 1024 + d]);
    const float sil = z / (1.f + __expf(-z));
    yout[row * 1024 + d] = f2bf((y + xcv * dpv) * sil);
  }
}

// ---------------------------------------------------------------- launch
extern "C" void kernel_launch(void* const* d_in, const int* in_sizes, int n_in,
                              void* d_out, int out_size, void* d_ws, size_t ws_size,
                              hipStream_t stream)
{
  (void)in_sizes; (void)n_in; (void)out_size; (void)ws_size;
  const float* src        = (const float*)d_in[0];
  const float* in_proj_w  = (const float*)d_in[1];
  const float* conv_w     = (const float*)d_in[2];
  const float* conv_b     = (const float*)d_in[3];
  const float* x_proj_w   = (const float*)d_in[4];
  const float* dt_proj_w  = (const float*)d_in[5];
  const float* dt_proj_b  = (const float*)d_in[6];
  const float* A_log      = (const float*)d_in[7];
  const float* Dp         = (const float*)d_in[8];
  const float* out_proj_w = (const float*)d_in[9];
  const float* mnorm_g    = (const float*)d_in[10];
  const float* mnorm_b    = (const float*)d_in[11];
  const float* n1_g       = (const float*)d_in[12];
  const float* n1_b       = (const float*)d_in[13];
  const float* n2_g       = (const float*)d_in[14];
  const float* n2_b       = (const float*)d_in[15];
  const float* n3_g       = (const float*)d_in[16];
  const float* n3_b       = (const float*)d_in[17];
  const float* ffn_w1     = (const float*)d_in[18];
  const float* ffn_w2     = (const float*)d_in[19];
  const float* fe_w       = (const float*)d_in[20];
  const float* fe_b       = (const float*)d_in[21];
  float* out = (float*)d_out;
  float* ws  = (float*)d_ws;

  // ---- workspace layout (float offsets; ranges disjoint — audited round 6) ----
  unsigned short* xzb  = (unsigned short*)ws;               // u16[0 .. 8388608)   = f[0 .. 4194304)
  unsigned short* xdblb= (unsigned short*)(ws + 4194304);   // u16 393216          = f[4194304 .. 4390912)
  unsigned short* dtwb = (unsigned short*)(ws + 4390912);   // u16 65536           = f[4390912 .. 4423680)
  // f[4423680 .. 8388608) free
  float* xc    = ws + 8388608;        // f[ 8388608 .. 12582912)
  float* xdbl  = ws + 12582912;       // f[12582912 .. 12976128), slot to 13107200
  float* delta = ws + 13107200;       // f[13107200 .. 17301504)
  float* s5    = ws + 17301504;       // f[17301504 .. 21495808)
  float* src1  = ws + 21495808;       // f[21495808 .. 25690112)
  float* hfin  = ws + 25690112;       // f[25690112 .. 26738688)
  float* pcum  = ws + 26738688;       // f[26738688 .. 27787264)
  float* hst   = ws + 27787264;       // f[27787264 .. 28835840)
  unsigned short* s1b  = (unsigned short*)(ws + 28835840);  // u16 4194304 = f[.. 30932992)
  unsigned short* xcb  = (unsigned short*)(ws + 30932992);  // u16 4194304 = f[.. 33030144)
  unsigned short* yb   = (unsigned short*)(ws + 33030144);  // u16 4194304 = f[.. 35127296)
  unsigned short* f1b  = (unsigned short*)(ws + 35127296);  // u16 16777216 = f[.. 43515904)
  unsigned short* ipwb = (unsigned short*)(ws + 43515904);  // u16 2097152 = f[.. 44564480)
  unsigned short* xpwb = (unsigned short*)(ws + 44564480);  // u16 98304   = f[.. 44613632)
  unsigned short* opwb = (unsigned short*)(ws + 44613632);  // u16 1048576 = f[.. 45137920)
  unsigned short* w1b  = (unsigned short*)(ws + 45137920);  // u16 4194304 = f[.. 47235072)
  unsigned short* w2b  = (unsigned short*)(ws + 47235072);  // u16 4194304 = f[.. 49332224)
  unsigned short* fewb = (unsigned short*)(ws + 49332224);  // u16 1048576 = f[.. 49856512)

  const dim3 blk(256);

  // 0. all weights -> bf16 (single launch; 3186688 float4s)
  cvt_all_kernel<<<12448, blk, 0, stream>>>(
      in_proj_w, x_proj_w, dt_proj_w, out_proj_w, ffn_w1, ffn_w2, fe_w,
      ipwb, xpwb, dtwb, opwb, w1b, w2b, fewb);

  // 1. x1 = LN(src; n1) -> bf16
  ln_kernel<<<NROWS, blk, 0, stream>>>(src, n1_g, n1_b, nullptr, nullptr, s1b);
  // 2. xz = x1 @ in_proj_w^T -> bf16  (4096x2048x1024)
  gemm_bf16_kernel<<<512, blk, 0, stream>>>(s1b, 1024, ipwb, 1024, xzb, 2048,
                                            nullptr, nullptr, 1024, 0, 1, 16, 0);
  // 3. x_c = silu(conv(x_in))  -> f32 + bf16
  conv_silu_kernel<<<16384, blk, 0, stream>>>(xzb, conv_w, conv_b, xc, xcb);
  // 4. x_dbl = x_c @ x_proj_w^T  (split-K=8, atomic f32)
  hipMemsetAsync(xdbl, 0, (size_t)NROWS * 96 * sizeof(float), stream);
  xproj_kernel<<<dim3(32, 8), blk, 0, stream>>>(xcb, 1024, xpwb, 1024, xdbl);
  // 4b. xdbl -> bf16 for dt_proj
  cvt_bf16_kernel<<<384, blk, 0, stream>>>(xdbl, xdblb, 98304);
  // 5. delta = softplus(dt @ dt_proj_w^T + b)  (4096x1024x64)
  gemm_bf16_kernel<<<256, blk, 0, stream>>>(xdblb, 96, dtwb, 64, delta, 1024,
                                            dt_proj_b, nullptr, 64, 1, 0, 8, 0);
  // 6-8. selective scan
  scan_pass1<<<256, blk, 0, stream>>>(delta, xc, xdbl, A_log, hfin, pcum);
  scan_pass2<<<128, blk, 0, stream>>>(hfin, pcum, hst);
  scan_pass3<<<256, blk, 0, stream>>>(delta, xc, xdbl, A_log, hst, Dp, xzb, yb);
  // 9. mamba_out = y @ out_proj_w^T  (4096x1024x1024), split-K=2, atomic into zeroed s5
  hipMemsetAsync(s5, 0, (size_t)NROWS * 1024 * sizeof(float), stream);
  gemm_bf16_kernel<<<dim3(256, 2), blk, 0, stream>>>(yb, 1024, opwb, 1024, s5, 1024,
                                                     nullptr, nullptr, 512, 0, 0, 8, 1);
  // 10. src1 = src + LN(mamba_out; mnorm)
  ln_kernel<<<NROWS, blk, 0, stream>>>(s5, mnorm_g, mnorm_b, src, src1, nullptr);
  // 11. x2 = LN(src1; n2) -> bf16
  ln_kernel<<<NROWS, blk, 0, stream>>>(src1, n2_g, n2_b, nullptr, nullptr, s1b);
  // 12. f1 = leaky(x2 @ ffn_w1^T) -> bf16  (4096x4096x1024)
  gemm_bf16_kernel<<<1024, blk, 0, stream>>>(s1b, 1024, w1b, 1024, f1b, 4096,
                                             nullptr, nullptr, 1024, 2, 1, 32, 0);
  // 13. src2 = src1 + f1 @ ffn_w2^T  (4096x1024x4096), split-K=4, seeded with src1
  hipMemcpyAsync(s5, src1, (size_t)NROWS * 1024 * sizeof(float),
                 hipMemcpyDeviceToDevice, stream);
  gemm_bf16_kernel<<<dim3(256, 4), blk, 0, stream>>>(f1b, 4096, w2b, 4096, s5, 1024,
                                                     nullptr, nullptr, 1024, 0, 0, 8, 1);
  // 14. x3 = LN(src2; n3) -> bf16
  ln_kernel<<<NROWS, blk, 0, stream>>>(s5, n3_g, n3_b, nullptr, nullptr, s1b);
  // 15. out = src2 + x3 @ fe_w^T + fe_b  (4096x1024x1024)
  gemm_bf16_kernel<<<256, blk, 0, stream>>>(s1b, 1024, fewb, 1024, out, 1024,
                                            fe_b, s5, 1024, 0, 0, 8, 0);
}

// Round 12
// 412.174 us; speedup vs baseline: 1.1899x; 1.1899x over previous
//
#include <hip/hip_runtime.h>
#include <hip/hip_bf16.h>
#include <cstddef>

#define L_SEQ   2048
#define NBATCH  2
#define NROWS   (NBATCH * L_SEQ)   /* 4096 */
#define NSTATE  16
#define CH      64
#define NCHUNK  (L_SEQ / CH)       /* 32 */

typedef __bf16 bf16x8 __attribute__((ext_vector_type(8)));
typedef float  f32x4  __attribute__((ext_vector_type(4)));
typedef unsigned short u16x4 __attribute__((ext_vector_type(4)));

static __device__ __forceinline__ unsigned short f2bf(float f) {
  unsigned int x = __builtin_bit_cast(unsigned int, f);
  x += 0x7fffu + ((x >> 16) & 1u);          // RNE
  return (unsigned short)(x >> 16);
}
static __device__ __forceinline__ float bf2f(unsigned short u) {
  return __builtin_bit_cast(float, ((unsigned int)u) << 16);
}

// async global->LDS, 16B per lane; LDS dest = wave-uniform base + lane*16
#define GLDS(g, l) __builtin_amdgcn_global_load_lds( \
    (const __attribute__((address_space(1))) void*)(g), \
    (__attribute__((address_space(3))) void*)(l), 16, 0, 0)

#define DRAIN_VM() asm volatile("s_waitcnt vmcnt(0)" ::: "memory")

// ---------------------------------------------------------------- f32 -> bf16 (generic, for xdbl)
__global__ __launch_bounds__(256) void cvt_bf16_kernel(
    const float* __restrict__ in, unsigned short* __restrict__ out, int n4)
{
  const int i = blockIdx.x * 256 + threadIdx.x;
  if (i < n4) {
    const float4 v = reinterpret_cast<const float4*>(in)[i];
    u16x4 o;
    o[0] = f2bf(v.x); o[1] = f2bf(v.y); o[2] = f2bf(v.z); o[3] = f2bf(v.w);
    reinterpret_cast<u16x4*>(out)[i] = o;
  }
}

// ---------------------------------------------------------------- all weights -> bf16, one launch
__global__ __launch_bounds__(256) void cvt_all_kernel(
    const float* __restrict__ ipw, const float* __restrict__ xpw,
    const float* __restrict__ dtw, const float* __restrict__ opw,
    const float* __restrict__ w1,  const float* __restrict__ w2,
    const float* __restrict__ few,
    unsigned short* __restrict__ o_ipw, unsigned short* __restrict__ o_xpw,
    unsigned short* __restrict__ o_dtw, unsigned short* __restrict__ o_opw,
    unsigned short* __restrict__ o_w1,  unsigned short* __restrict__ o_w2,
    unsigned short* __restrict__ o_few)
{
  int i = blockIdx.x * 256 + threadIdx.x;
  const float* src; unsigned short* dst;
  if (i < 524288)                 { src = ipw; dst = o_ipw; }
  else if ((i -= 524288) < 24576) { src = xpw; dst = o_xpw; }
  else if ((i -= 24576) < 16384)  { src = dtw; dst = o_dtw; }
  else if ((i -= 16384) < 262144) { src = opw; dst = o_opw; }
  else if ((i -= 262144) < 1048576){ src = w1; dst = o_w1; }
  else if ((i -= 1048576) < 1048576){ src = w2; dst = o_w2; }
  else if ((i -= 1048576) < 262144){ src = few; dst = o_few; }
  else return;
  const float4 v = reinterpret_cast<const float4*>(src)[i];
  u16x4 o;
  o[0] = f2bf(v.x); o[1] = f2bf(v.y); o[2] = f2bf(v.z); o[3] = f2bf(v.w);
  reinterpret_cast<u16x4*>(dst)[i] = o;
}

// ---------------------------------------------------------------- LayerNorm
__global__ __launch_bounds__(256) void ln_kernel(
    const float* __restrict__ in, const float* __restrict__ g,
    const float* __restrict__ bta, const float* __restrict__ res,
    float* __restrict__ out, unsigned short* __restrict__ outb)
{
  const int row = blockIdx.x;
  const int tid = threadIdx.x;
  __shared__ float sm[8];
  const float4 v = reinterpret_cast<const float4*>(in + (size_t)row * 1024)[tid];
  float s = v.x + v.y + v.z + v.w;
#pragma unroll
  for (int o = 32; o > 0; o >>= 1) s += __shfl_down(s, o, 64);
  if ((tid & 63) == 0) sm[tid >> 6] = s;
  __syncthreads();
  const float mean = (sm[0] + sm[1] + sm[2] + sm[3]) * (1.f / 1024.f);
  const float dx = v.x - mean, dy = v.y - mean, dz = v.z - mean, dw = v.w - mean;
  float q = dx * dx + dy * dy + dz * dz + dw * dw;
#pragma unroll
  for (int o = 32; o > 0; o >>= 1) q += __shfl_down(q, o, 64);
  __syncthreads();
  if ((tid & 63) == 0) sm[tid >> 6] = q;
  __syncthreads();
  const float var = (sm[0] + sm[1] + sm[2] + sm[3]) * (1.f / 1024.f);
  const float rstd = rsqrtf(var + 1e-5f);
  const float4 gv = reinterpret_cast<const float4*>(g)[tid];
  const float4 bv = reinterpret_cast<const float4*>(bta)[tid];
  float4 o4;
  o4.x = dx * rstd * gv.x + bv.x;
  o4.y = dy * rstd * gv.y + bv.y;
  o4.z = dz * rstd * gv.z + bv.z;
  o4.w = dw * rstd * gv.w + bv.w;
  if (outb) {
    u16x4 ob;
    ob[0] = f2bf(o4.x); ob[1] = f2bf(o4.y); ob[2] = f2bf(o4.z); ob[3] = f2bf(o4.w);
    reinterpret_cast<u16x4*>(outb + (size_t)row * 1024)[tid] = ob;
  } else {
    if (res) {
      const float4 rv = reinterpret_cast<const float4*>(res + (size_t)row * 1024)[tid];
      o4.x += rv.x; o4.y += rv.y; o4.z += rv.z; o4.w += rv.w;
    }
    reinterpret_cast<float4*>(out + (size_t)row * 1024)[tid] = o4;
  }
}

// ---------------------------------------------------------------- bf16 GEMM, 2-phase pipelined (round-8 proven)
// C[M][N] = act(A[M][K] @ B[N][K]^T + bias) + res ; tiles 128x128, BK=32
// 1D grid = (M/128)*gy with bijective XCD-chunked swizzle; gy = N/128.
__global__ __launch_bounds__(256) void gemm_bf16_kernel(
    const unsigned short* __restrict__ A, int lda,
    const unsigned short* __restrict__ B, int ldb,
    void* __restrict__ Cv, int ldc,
    const float* __restrict__ bias, const float* __restrict__ res,
    int K, int act, int outbf, int gy)
{
  __shared__ unsigned short As[2][128 * 32];
  __shared__ unsigned short Bs[2][128 * 32];
  const int t = threadIdx.x;
  const int w = t >> 6, l = t & 63;

  const int q = gridDim.x >> 3;
  const int nid = (blockIdx.x & 7) * q + (blockIdx.x >> 3);
  const int bm = (nid / gy) * 128;
  const int bn = (nid % gy) * 128;

  const int wr = (w >> 1) * 64, wc = (w & 1) * 64;
  f32x4 acc[4][4] = {};

  const int srow = t >> 2;          // 0..63
  const int sk = (t & 3) * 8;
  const unsigned short* gA0 = A + (size_t)(bm + srow) * lda + sk;
  const unsigned short* gA1 = gA0 + (size_t)64 * lda;
  const unsigned short* gB0 = B + (size_t)(bn + srow) * ldb + sk;
  const unsigned short* gB1 = gB0 + (size_t)64 * ldb;

  const int fr = l & 15;
  const int kb = (l >> 4) * 8;

#define STAGE(buf, k0) do { \
    GLDS(gA0 + (k0), &As[buf][w * 512]); \
    GLDS(gA1 + (k0), &As[buf][2048 + w * 512]); \
    GLDS(gB0 + (k0), &Bs[buf][w * 512]); \
    GLDS(gB1 + (k0), &Bs[buf][2048 + w * 512]); \
  } while (0)

#define COMPUTE(buf) do { \
    bf16x8 af[4], bfr[4]; \
    _Pragma("unroll") \
    for (int i = 0; i < 4; ++i) \
      af[i] = *reinterpret_cast<const bf16x8*>(&As[buf][(wr + i * 16 + fr) * 32 + kb]); \
    _Pragma("unroll") \
    for (int j = 0; j < 4; ++j) \
      bfr[j] = *reinterpret_cast<const bf16x8*>(&Bs[buf][(wc + j * 16 + fr) * 32 + kb]); \
    _Pragma("unroll") \
    for (int i = 0; i < 4; ++i) \
      _Pragma("unroll") \
      for (int j = 0; j < 4; ++j) \
        acc[i][j] = __builtin_amdgcn_mfma_f32_16x16x32_bf16(af[i], bfr[j], acc[i][j], 0, 0, 0); \
  } while (0)

  STAGE(0, 0);
  DRAIN_VM();
  __syncthreads();
  int cur = 0;
  for (int k0 = 32; k0 < K; k0 += 32) {
    __builtin_amdgcn_sched_barrier(0);
    STAGE(cur ^ 1, k0);
    __builtin_amdgcn_sched_barrier(0);
    COMPUTE(cur);
    DRAIN_VM();
    __syncthreads();
    cur ^= 1;
  }
  COMPUTE(cur);
#undef STAGE
#undef COMPUTE

  const int crow = (l >> 4) * 4;
  const int ccol = l & 15;
  float* Cf = (float*)Cv;
  unsigned short* Cb = (unsigned short*)Cv;
#pragma unroll
  for (int i = 0; i < 4; ++i) {
#pragma unroll
    for (int j = 0; j < 4; ++j) {
      const int n = bn + wc + j * 16 + ccol;
      const float bv = bias ? bias[n] : 0.f;
#pragma unroll
      for (int r = 0; r < 4; ++r) {
        const int m = bm + wr + i * 16 + crow + r;
        float v = acc[i][j][r] + bv;
        if (act == 1) v = (v > 20.f) ? v : __logf(1.f + __expf(v));
        else if (act == 2) v = (v >= 0.f) ? v : 0.01f * v;
        if (res) v += res[(size_t)m * ldc + n];
        if (outbf) Cb[(size_t)m * ldc + n] = f2bf(v);
        else       Cf[(size_t)m * ldc + n] = v;
      }
    }
  }
}

// ---------------------------------------------------------------- bf16 GEMM, intra-block K-split
// 512 threads = 2 groups x 4 waves. Group g computes K-half [g*K/2,(g+1)*K/2)
// with its own LDS double-buffer (round-8 proven loop). Then group 1 stores
// acc into LDS (staging reused post-barrier), group 0 adds + epilogue.
// No extra HBM traffic, serial K-chain halved, 2 waves/SIMD.
__global__ __launch_bounds__(512) void gemm_ksplit_kernel(
    const unsigned short* __restrict__ A, int lda,
    const unsigned short* __restrict__ B, int ldb,
    void* __restrict__ Cv, int ldc,
    const float* __restrict__ bias, const float* __restrict__ res,
    int K, int act, int outbf, int gy)
{
  __shared__ __align__(16) unsigned char smem[65536];
  const int tid = threadIdx.x;
  const int grp = tid >> 8;         // 0 or 1
  const int t = tid & 255;
  const int w = t >> 6, l = t & 63;

  const int q = gridDim.x >> 3;
  const int nid = (blockIdx.x & 7) * q + (blockIdx.x >> 3);
  const int bm = (nid / gy) * 128;
  const int bn = (nid % gy) * 128;

  const int K2 = K >> 1;
  const int koff = grp * K2;
  const int wr = (w >> 1) * 64, wc = (w & 1) * 64;
  f32x4 acc[4][4] = {};

  const int srow = t >> 2;
  const int sk = (t & 3) * 8;
  const unsigned short* gA0 = A + (size_t)(bm + srow) * lda + koff + sk;
  const unsigned short* gA1 = gA0 + (size_t)64 * lda;
  const unsigned short* gB0 = B + (size_t)(bn + srow) * ldb + koff + sk;
  const unsigned short* gB1 = gB0 + (size_t)64 * ldb;

  // LDS: A staging [0,32768) = grp*16384 + buf*8192 ; B staging [32768,65536)
  const int gbase = grp * 16384;

  const int fr = l & 15;
  const int kb = (l >> 4) * 8;

#define SA(buf) ((unsigned short*)(smem + gbase + (buf) * 8192))
#define SB(buf) ((unsigned short*)(smem + 32768 + gbase + (buf) * 8192))

#define STAGEK(buf, k0) do { \
    GLDS(gA0 + (k0), SA(buf) + w * 512); \
    GLDS(gA1 + (k0), SA(buf) + 2048 + w * 512); \
    GLDS(gB0 + (k0), SB(buf) + w * 512); \
    GLDS(gB1 + (k0), SB(buf) + 2048 + w * 512); \
  } while (0)

#define COMPUTEK(buf) do { \
    bf16x8 af[4], bfr[4]; \
    _Pragma("unroll") \
    for (int i = 0; i < 4; ++i) \
      af[i] = *reinterpret_cast<const bf16x8*>(SA(buf) + (wr + i * 16 + fr) * 32 + kb); \
    _Pragma("unroll") \
    for (int j = 0; j < 4; ++j) \
      bfr[j] = *reinterpret_cast<const bf16x8*>(SB(buf) + (wc + j * 16 + fr) * 32 + kb); \
    _Pragma("unroll") \
    for (int i = 0; i < 4; ++i) \
      _Pragma("unroll") \
      for (int j = 0; j < 4; ++j) \
        acc[i][j] = __builtin_amdgcn_mfma_f32_16x16x32_bf16(af[i], bfr[j], acc[i][j], 0, 0, 0); \
  } while (0)

  STAGEK(0, 0);
  DRAIN_VM();
  __syncthreads();
  int cur = 0;
  for (int k0 = 32; k0 < K2; k0 += 32) {
    __builtin_amdgcn_sched_barrier(0);
    STAGEK(cur ^ 1, k0);
    __builtin_amdgcn_sched_barrier(0);
    COMPUTEK(cur);
    DRAIN_VM();
    __syncthreads();
    cur ^= 1;
  }
  COMPUTEK(cur);
#undef STAGEK
#undef COMPUTEK
#undef SA
#undef SB

  // cross-group reduction: staging LDS reused as 64KB f32 buffer
  __syncthreads();                       // all staging reads complete
  float* red = (float*)smem;             // 256 threads x 64 floats
  if (grp) {
#pragma unroll
    for (int i = 0; i < 4; ++i)
#pragma unroll
      for (int j = 0; j < 4; ++j)
        *reinterpret_cast<f32x4*>(&red[(t << 6) + (i * 4 + j) * 4]) = acc[i][j];
  }
  __syncthreads();
  if (!grp) {
    const int crow = (l >> 4) * 4;
    const int ccol = l & 15;
    float* Cf = (float*)Cv;
    unsigned short* Cb = (unsigned short*)Cv;
#pragma unroll
    for (int i = 0; i < 4; ++i) {
#pragma unroll
      for (int j = 0; j < 4; ++j) {
        const f32x4 o = *reinterpret_cast<const f32x4*>(&red[(t << 6) + (i * 4 + j) * 4]);
        const int n = bn + wc + j * 16 + ccol;
        const float bv = bias ? bias[n] : 0.f;
#pragma unroll
        for (int r = 0; r < 4; ++r) {
          const int m = bm + wr + i * 16 + crow + r;
          float v = acc[i][j][r] + o[r] + bv;
          if (act == 1) v = (v > 20.f) ? v : __logf(1.f + __expf(v));
          else if (act == 2) v = (v >= 0.f) ? v : 0.01f * v;
          if (res) v += res[(size_t)m * ldc + n];
          if (outbf) Cb[(size_t)m * ldc + n] = f2bf(v);
          else       Cf[(size_t)m * ldc + n] = v;
        }
      }
    }
  }
}

// ---------------------------------------------------------------- x_proj split-K (N=96), 2-phase (proven)
__global__ __launch_bounds__(256) void xproj_kernel(
    const unsigned short* __restrict__ A, int lda,
    const unsigned short* __restrict__ B, int ldb,
    float* __restrict__ C)
{
  __shared__ unsigned short As[2][128 * 32];
  __shared__ unsigned short Bs[2][96 * 32];
  const int t = threadIdx.x;
  const int w = t >> 6, l = t & 63;
  const int bm = blockIdx.x * 128;
  const int kbase = blockIdx.y * 128;

  f32x4 acc[2][6] = {};

  const int srow = t >> 2;
  const int sk = (t & 3) * 8;
  const unsigned short* gA0 = A + (size_t)(bm + srow) * lda + kbase + sk;
  const unsigned short* gA1 = gA0 + (size_t)64 * lda;
  const unsigned short* gB0 = B + (size_t)srow * ldb + kbase + sk;
  const unsigned short* gB1 = gB0 + (size_t)64 * ldb;

  const int fr = l & 15;
  const int kb = (l >> 4) * 8;

#define STAGEX(buf, k0) do { \
    GLDS(gA0 + (k0), &As[buf][w * 512]); \
    GLDS(gA1 + (k0), &As[buf][2048 + w * 512]); \
    GLDS(gB0 + (k0), &Bs[buf][w * 512]); \
    if (w < 2) GLDS(gB1 + (k0), &Bs[buf][2048 + w * 512]); \
  } while (0)

#define COMPUTEX(buf) do { \
    bf16x8 af[2], bfr[6]; \
    _Pragma("unroll") \
    for (int i = 0; i < 2; ++i) \
      af[i] = *reinterpret_cast<const bf16x8*>(&As[buf][(w * 32 + i * 16 + fr) * 32 + kb]); \
    _Pragma("unroll") \
    for (int j = 0; j < 6; ++j) \
      bfr[j] = *reinterpret_cast<const bf16x8*>(&Bs[buf][(j * 16 + fr) * 32 + kb]); \
    _Pragma("unroll") \
    for (int i = 0; i < 2; ++i) \
      _Pragma("unroll") \
      for (int j = 0; j < 6; ++j) \
        acc[i][j] = __builtin_amdgcn_mfma_f32_16x16x32_bf16(af[i], bfr[j], acc[i][j], 0, 0, 0); \
  } while (0)

  STAGEX(0, 0);
  DRAIN_VM();
  __syncthreads();
  int cur = 0;
  for (int s = 1; s < 4; ++s) {
    __builtin_amdgcn_sched_barrier(0);
    STAGEX(cur ^ 1, s * 32);
    __builtin_amdgcn_sched_barrier(0);
    COMPUTEX(cur);
    DRAIN_VM();
    __syncthreads();
    cur ^= 1;
  }
  COMPUTEX(cur);
#undef STAGEX
#undef COMPUTEX

  const int crow = (l >> 4) * 4;
  const int ccol = l & 15;
#pragma unroll
  for (int i = 0; i < 2; ++i)
#pragma unroll
    for (int j = 0; j < 6; ++j)
#pragma unroll
      for (int r = 0; r < 4; ++r) {
        const int m = bm + w * 32 + i * 16 + crow + r;
        const int n = j * 16 + ccol;
        atomicAdd(&C[(size_t)m * 96 + n], acc[i][j][r]);
      }
}

// ---------------------------------------------------------------- conv(k=2)+SiLU (bf16 xz)
__global__ __launch_bounds__(256) void conv_silu_kernel(
    const unsigned short* __restrict__ xz, const float* __restrict__ cw,
    const float* __restrict__ cb, float* __restrict__ xc,
    unsigned short* __restrict__ xcb)
{
  const int idx = blockIdx.x * 256 + threadIdx.x;   // over 4096*1024
  const int row = idx >> 10;
  const int d = idx & 1023;
  const int l = row & (L_SEQ - 1);
  const float cur = bf2f(xz[(size_t)row * 2048 + d]);
  const float prev = (l == 0) ? 0.f : bf2f(xz[(size_t)(row - 1) * 2048 + d]);
  const float v = prev * cw[d * 2 + 0] + cur * cw[d * 2 + 1] + cb[d];
  const float sv = v / (1.f + __expf(-v));
  xc[idx] = sv;
  xcb[idx] = f2bf(sv);
}

// ---------------------------------------------------------------- scan pass 1
__global__ __launch_bounds__(256) void scan_pass1(
    const float* __restrict__ delta, const float* __restrict__ xc,
    const float* __restrict__ xdbl, const float* __restrict__ A_log,
    float* __restrict__ hfin, float* __restrict__ pcum)
{
  const int tid = threadIdx.x;
  const int db = blockIdx.x & 3;
  const int c = (blockIdx.x >> 2) & (NCHUNK - 1);
  const int b = blockIdx.x >> 7;
  const int d = db * 256 + tid;
  __shared__ float Bsh[CH][16];
  {
    const int lr = tid >> 2, q = tid & 3;
    const float* p = xdbl + ((size_t)(b * L_SEQ + c * CH + lr) * 96) + 64 + q * 4;
    *reinterpret_cast<float4*>(&Bsh[lr][q * 4]) = *reinterpret_cast<const float4*>(p);
  }
  float a[NSTATE];
#pragma unroll
  for (int n = 0; n < NSTATE; ++n) a[n] = -__expf(A_log[d * 16 + n]);
  __syncthreads();
  float h[NSTATE], P[NSTATE];
#pragma unroll
  for (int n = 0; n < NSTATE; ++n) { h[n] = 0.f; P[n] = 1.f; }
  const size_t rowbase = (size_t)(b * L_SEQ + c * CH);
  for (int s = 0; s < CH; ++s) {
    const size_t row = rowbase + s;
    const float dl = delta[row * 1024 + d];
    const float xcv = xc[row * 1024 + d];
#pragma unroll
    for (int n = 0; n < NSTATE; ++n) {
      const float dA = __expf(dl * a[n]);
      h[n] = h[n] * dA + (dl * Bsh[s][n]) * xcv;
      P[n] *= dA;
    }
  }
  const size_t base = ((size_t)((b * NCHUNK + c) * 1024 + d)) * 16;
  float4* hp = reinterpret_cast<float4*>(hfin + base);
  float4* pp = reinterpret_cast<float4*>(pcum + base);
#pragma unroll
  for (int qq = 0; qq < 4; ++qq) {
    hp[qq] = make_float4(h[qq * 4], h[qq * 4 + 1], h[qq * 4 + 2], h[qq * 4 + 3]);
    pp[qq] = make_float4(P[qq * 4], P[qq * 4 + 1], P[qq * 4 + 2], P[qq * 4 + 3]);
  }
}

// ---------------------------------------------------------------- scan pass 2
__global__ __launch_bounds__(256) void scan_pass2(
    const float* __restrict__ hfin, const float* __restrict__ pcum,
    float* __restrict__ hstart)
{
  const int t = blockIdx.x * 256 + threadIdx.x;
  const int b = t >> 14;
  const int dn = t & 16383;
  const size_t base = (size_t)b * NCHUNK * 16384 + dn;
  float h = 0.f;
  for (int c = 0; c < NCHUNK; ++c) {
    const size_t idx = base + (size_t)c * 16384;
    hstart[idx] = h;
    h = pcum[idx] * h + hfin[idx];
  }
}

// ---------------------------------------------------------------- scan pass 3 (bf16 y out, bf16 z in)
__global__ __launch_bounds__(256) void scan_pass3(
    const float* __restrict__ delta, const float* __restrict__ xc,
    const float* __restrict__ xdbl, const float* __restrict__ A_log,
    const float* __restrict__ hstart, const float* __restrict__ Dp,
    const unsigned short* __restrict__ xz, unsigned short* __restrict__ yout)
{
  const int tid = threadIdx.x;
  const int db = blockIdx.x & 3;
  const int c = (blockIdx.x >> 2) & (NCHUNK - 1);
  const int b = blockIdx.x >> 7;
  const int d = db * 256 + tid;
  __shared__ float Bsh[CH][16];
  __shared__ float Csh[CH][16];
  {
    const int lr = tid >> 2, q = tid & 3;
    const float* p = xdbl + ((size_t)(b * L_SEQ + c * CH + lr) * 96);
    *reinterpret_cast<float4*>(&Bsh[lr][q * 4]) = *reinterpret_cast<const float4*>(p + 64 + q * 4);
    *reinterpret_cast<float4*>(&Csh[lr][q * 4]) = *reinterpret_cast<const float4*>(p + 80 + q * 4);
  }
  float a[NSTATE];
#pragma unroll
  for (int n = 0; n < NSTATE; ++n) a[n] = -__expf(A_log[d * 16 + n]);
  float h[NSTATE];
  {
    const size_t base = ((size_t)((b * NCHUNK + c) * 1024 + d)) * 16;
    const float4* hp = reinterpret_cast<const float4*>(hstart + base);
#pragma unroll
    for (int qq = 0; qq < 4; ++qq) {
      const float4 v = hp[qq];
      h[qq * 4] = v.x; h[qq * 4 + 1] = v.y; h[qq * 4 + 2] = v.z; h[qq * 4 + 3] = v.w;
    }
  }
  const float dpv = Dp[d];
  __syncthreads();
  const size_t rowbase = (size_t)(b * L_SEQ + c * CH);
  for (int s = 0; s < CH; ++s) {
    const size_t row = rowbase + s;
    const float dl = delta[row * 1024 + d];
    const float xcv = xc[row * 1024 + d];
    float y = 0.f;
#pragma unroll
    for (int n = 0; n < NSTATE; ++n) {
      const float dA = __expf(dl * a[n]);
      h[n] = h[n] * dA + (dl * Bsh[s][n]) * xcv;
      y += h[n] * Csh[s][n];
    }
    const float z = bf2f(xz[row * 2048 + 1024 + d]);
    const float sil = z / (1.f + __expf(-z));
    yout[row * 1024 + d] = f2bf((y + xcv * dpv) * sil);
  }
}

// ---------------------------------------------------------------- launch
extern "C" void kernel_launch(void* const* d_in, const int* in_sizes, int n_in,
                              void* d_out, int out_size, void* d_ws, size_t ws_size,
                              hipStream_t stream)
{
  (void)in_sizes; (void)n_in; (void)out_size; (void)ws_size;
  const float* src        = (const float*)d_in[0];
  const float* in_proj_w  = (const float*)d_in[1];
  const float* conv_w     = (const float*)d_in[2];
  const float* conv_b     = (const float*)d_in[3];
  const float* x_proj_w   = (const float*)d_in[4];
  const float* dt_proj_w  = (const float*)d_in[5];
  const float* dt_proj_b  = (const float*)d_in[6];
  const float* A_log      = (const float*)d_in[7];
  const float* Dp         = (const float*)d_in[8];
  const float* out_proj_w = (const float*)d_in[9];
  const float* mnorm_g    = (const float*)d_in[10];
  const float* mnorm_b    = (const float*)d_in[11];
  const float* n1_g       = (const float*)d_in[12];
  const float* n1_b       = (const float*)d_in[13];
  const float* n2_g       = (const float*)d_in[14];
  const float* n2_b       = (const float*)d_in[15];
  const float* n3_g       = (const float*)d_in[16];
  const float* n3_b       = (const float*)d_in[17];
  const float* ffn_w1     = (const float*)d_in[18];
  const float* ffn_w2     = (const float*)d_in[19];
  const float* fe_w       = (const float*)d_in[20];
  const float* fe_b       = (const float*)d_in[21];
  float* out = (float*)d_out;
  float* ws  = (float*)d_ws;

  // ---- workspace layout (float offsets; ranges disjoint — audited round 6) ----
  unsigned short* xzb  = (unsigned short*)ws;               // u16[0 .. 8388608)   = f[0 .. 4194304)
  unsigned short* xdblb= (unsigned short*)(ws + 4194304);   // u16 393216          = f[4194304 .. 4390912)
  unsigned short* dtwb = (unsigned short*)(ws + 4390912);   // u16 65536           = f[4390912 .. 4423680)
  float* xc    = ws + 8388608;        // f[ 8388608 .. 12582912)
  float* xdbl  = ws + 12582912;       // f[12582912 .. 12976128), slot to 13107200
  float* delta = ws + 13107200;       // f[13107200 .. 17301504)
  float* s5    = ws + 17301504;       // f[17301504 .. 21495808)
  float* src1  = ws + 21495808;       // f[21495808 .. 25690112)
  float* hfin  = ws + 25690112;       // f[25690112 .. 26738688)
  float* pcum  = ws + 26738688;       // f[26738688 .. 27787264)
  float* hst   = ws + 27787264;       // f[27787264 .. 28835840)
  unsigned short* s1b  = (unsigned short*)(ws + 28835840);  // u16 4194304 = f[.. 30932992)
  unsigned short* xcb  = (unsigned short*)(ws + 30932992);  // u16 4194304 = f[.. 33030144)
  unsigned short* yb   = (unsigned short*)(ws + 33030144);  // u16 4194304 = f[.. 35127296)
  unsigned short* f1b  = (unsigned short*)(ws + 35127296);  // u16 16777216 = f[.. 43515904)
  unsigned short* ipwb = (unsigned short*)(ws + 43515904);  // u16 2097152 = f[.. 44564480)
  unsigned short* xpwb = (unsigned short*)(ws + 44564480);  // u16 98304   = f[.. 44613632)
  unsigned short* opwb = (unsigned short*)(ws + 44613632);  // u16 1048576 = f[.. 45137920)
  unsigned short* w1b  = (unsigned short*)(ws + 45137920);  // u16 4194304 = f[.. 47235072)
  unsigned short* w2b  = (unsigned short*)(ws + 47235072);  // u16 4194304 = f[.. 49332224)
  unsigned short* fewb = (unsigned short*)(ws + 49332224);  // u16 1048576 = f[.. 49856512)

  const dim3 blk(256);
  const dim3 blk512(512);

  // 0. all weights -> bf16 (single launch; 3186688 float4s)
  cvt_all_kernel<<<12448, blk, 0, stream>>>(
      in_proj_w, x_proj_w, dt_proj_w, out_proj_w, ffn_w1, ffn_w2, fe_w,
      ipwb, xpwb, dtwb, opwb, w1b, w2b, fewb);

  // 1. x1 = LN(src; n1) -> bf16
  ln_kernel<<<NROWS, blk, 0, stream>>>(src, n1_g, n1_b, nullptr, nullptr, s1b);
  // 2. xz = x1 @ in_proj_w^T -> bf16  (4096x2048x1024, intra-block K-split)
  gemm_ksplit_kernel<<<512, blk512, 0, stream>>>(s1b, 1024, ipwb, 1024, xzb, 2048,
                                                 nullptr, nullptr, 1024, 0, 1, 16);
  // 3. x_c = silu(conv(x_in))  -> f32 + bf16
  conv_silu_kernel<<<16384, blk, 0, stream>>>(xzb, conv_w, conv_b, xc, xcb);
  // 4. x_dbl = x_c @ x_proj_w^T  (split-K=8, atomic f32)
  hipMemsetAsync(xdbl, 0, (size_t)NROWS * 96 * sizeof(float), stream);
  xproj_kernel<<<dim3(32, 8), blk, 0, stream>>>(xcb, 1024, xpwb, 1024, xdbl);
  // 4b. xdbl -> bf16 for dt_proj
  cvt_bf16_kernel<<<384, blk, 0, stream>>>(xdbl, xdblb, 98304);
  // 5. delta = softplus(dt @ dt_proj_w^T + b)  (4096x1024x64)
  gemm_bf16_kernel<<<256, blk, 0, stream>>>(xdblb, 96, dtwb, 64, delta, 1024,
                                            dt_proj_b, nullptr, 64, 1, 0, 8);
  // 6-8. selective scan
  scan_pass1<<<256, blk, 0, stream>>>(delta, xc, xdbl, A_log, hfin, pcum);
  scan_pass2<<<128, blk, 0, stream>>>(hfin, pcum, hst);
  scan_pass3<<<256, blk, 0, stream>>>(delta, xc, xdbl, A_log, hst, Dp, xzb, yb);
  // 9. mamba_out = y @ out_proj_w^T  (4096x1024x1024, intra-block K-split)
  gemm_ksplit_kernel<<<256, blk512, 0, stream>>>(yb, 1024, opwb, 1024, s5, 1024,
                                                 nullptr, nullptr, 1024, 0, 0, 8);
  // 10. src1 = src + LN(mamba_out; mnorm)
  ln_kernel<<<NROWS, blk, 0, stream>>>(s5, mnorm_g, mnorm_b, src, src1, nullptr);
  // 11. x2 = LN(src1; n2) -> bf16
  ln_kernel<<<NROWS, blk, 0, stream>>>(src1, n2_g, n2_b, nullptr, nullptr, s1b);
  // 12. f1 = leaky(x2 @ ffn_w1^T) -> bf16  (4096x4096x1024)
  gemm_bf16_kernel<<<1024, blk, 0, stream>>>(s1b, 1024, w1b, 1024, f1b, 4096,
                                             nullptr, nullptr, 1024, 2, 1, 32);
  // 13. src2 = src1 + f1 @ ffn_w2^T  (4096x1024x4096, intra-block K-split)
  gemm_ksplit_kernel<<<256, blk512, 0, stream>>>(f1b, 4096, w2b, 4096, s5, 1024,
                                                 nullptr, src1, 4096, 0, 0, 8);
  // 14. x3 = LN(src2; n3) -> bf16
  ln_kernel<<<NROWS, blk, 0, stream>>>(s5, n3_g, n3_b, nullptr, nullptr, s1b);
  // 15. out = src2 + x3 @ fe_w^T + fe_b  (4096x1024x1024, intra-block K-split)
  gemm_ksplit_kernel<<<256, blk512, 0, stream>>>(s1b, 1024, fewb, 1024, out, 1024,
                                                 fe_b, s5, 1024, 0, 0, 8);
}

// Round 14
// 406.477 us; speedup vs baseline: 1.2065x; 1.0140x over previous
//
#include <hip/hip_runtime.h>
#include <hip/hip_bf16.h>
#include <cstddef>

#define L_SEQ   2048
#define NBATCH  2
#define NROWS   (NBATCH * L_SEQ)   /* 4096 */
#define NSTATE  16
#define CH      64
#define NCHUNK  (L_SEQ / CH)       /* 32 */

typedef __bf16 bf16x8 __attribute__((ext_vector_type(8)));
typedef float  f32x4  __attribute__((ext_vector_type(4)));
typedef unsigned short u16x4 __attribute__((ext_vector_type(4)));

static __device__ __forceinline__ unsigned short f2bf(float f) {
  unsigned int x = __builtin_bit_cast(unsigned int, f);
  x += 0x7fffu + ((x >> 16) & 1u);          // RNE
  return (unsigned short)(x >> 16);
}
static __device__ __forceinline__ float bf2f(unsigned short u) {
  return __builtin_bit_cast(float, ((unsigned int)u) << 16);
}

// async global->LDS, 16B per lane; LDS dest = wave-uniform base + lane*16
#define GLDS(g, l) __builtin_amdgcn_global_load_lds( \
    (const __attribute__((address_space(1))) void*)(g), \
    (__attribute__((address_space(3))) void*)(l), 16, 0, 0)

#define DRAIN_VM() asm volatile("s_waitcnt vmcnt(0)" ::: "memory")

// ---------------------------------------------------------------- f32 -> bf16 (generic, for xdbl)
__global__ __launch_bounds__(256) void cvt_bf16_kernel(
    const float* __restrict__ in, unsigned short* __restrict__ out, int n4)
{
  const int i = blockIdx.x * 256 + threadIdx.x;
  if (i < n4) {
    const float4 v = reinterpret_cast<const float4*>(in)[i];
    u16x4 o;
    o[0] = f2bf(v.x); o[1] = f2bf(v.y); o[2] = f2bf(v.z); o[3] = f2bf(v.w);
    reinterpret_cast<u16x4*>(out)[i] = o;
  }
}

// ---------------------------------------------------------------- all weights -> bf16, one launch
__global__ __launch_bounds__(256) void cvt_all_kernel(
    const float* __restrict__ ipw, const float* __restrict__ xpw,
    const float* __restrict__ dtw, const float* __restrict__ opw,
    const float* __restrict__ w1,  const float* __restrict__ w2,
    const float* __restrict__ few,
    unsigned short* __restrict__ o_ipw, unsigned short* __restrict__ o_xpw,
    unsigned short* __restrict__ o_dtw, unsigned short* __restrict__ o_opw,
    unsigned short* __restrict__ o_w1,  unsigned short* __restrict__ o_w2,
    unsigned short* __restrict__ o_few)
{
  int i = blockIdx.x * 256 + threadIdx.x;
  const float* src; unsigned short* dst;
  if (i < 524288)                 { src = ipw; dst = o_ipw; }
  else if ((i -= 524288) < 24576) { src = xpw; dst = o_xpw; }
  else if ((i -= 24576) < 16384)  { src = dtw; dst = o_dtw; }
  else if ((i -= 16384) < 262144) { src = opw; dst = o_opw; }
  else if ((i -= 262144) < 1048576){ src = w1; dst = o_w1; }
  else if ((i -= 1048576) < 1048576){ src = w2; dst = o_w2; }
  else if ((i -= 1048576) < 262144){ src = few; dst = o_few; }
  else return;
  const float4 v = reinterpret_cast<const float4*>(src)[i];
  u16x4 o;
  o[0] = f2bf(v.x); o[1] = f2bf(v.y); o[2] = f2bf(v.z); o[3] = f2bf(v.w);
  reinterpret_cast<u16x4*>(dst)[i] = o;
}

// ---------------------------------------------------------------- LayerNorm
__global__ __launch_bounds__(256) void ln_kernel(
    const float* __restrict__ in, const float* __restrict__ g,
    const float* __restrict__ bta, const float* __restrict__ res,
    float* __restrict__ out, unsigned short* __restrict__ outb)
{
  const int row = blockIdx.x;
  const int tid = threadIdx.x;
  __shared__ float sm[8];
  const float4 v = reinterpret_cast<const float4*>(in + (size_t)row * 1024)[tid];
  float s = v.x + v.y + v.z + v.w;
#pragma unroll
  for (int o = 32; o > 0; o >>= 1) s += __shfl_down(s, o, 64);
  if ((tid & 63) == 0) sm[tid >> 6] = s;
  __syncthreads();
  const float mean = (sm[0] + sm[1] + sm[2] + sm[3]) * (1.f / 1024.f);
  const float dx = v.x - mean, dy = v.y - mean, dz = v.z - mean, dw = v.w - mean;
  float q = dx * dx + dy * dy + dz * dz + dw * dw;
#pragma unroll
  for (int o = 32; o > 0; o >>= 1) q += __shfl_down(q, o, 64);
  __syncthreads();
  if ((tid & 63) == 0) sm[tid >> 6] = q;
  __syncthreads();
  const float var = (sm[0] + sm[1] + sm[2] + sm[3]) * (1.f / 1024.f);
  const float rstd = rsqrtf(var + 1e-5f);
  const float4 gv = reinterpret_cast<const float4*>(g)[tid];
  const float4 bv = reinterpret_cast<const float4*>(bta)[tid];
  float4 o4;
  o4.x = dx * rstd * gv.x + bv.x;
  o4.y = dy * rstd * gv.y + bv.y;
  o4.z = dz * rstd * gv.z + bv.z;
  o4.w = dw * rstd * gv.w + bv.w;
  if (outb) {
    u16x4 ob;
    ob[0] = f2bf(o4.x); ob[1] = f2bf(o4.y); ob[2] = f2bf(o4.z); ob[3] = f2bf(o4.w);
    reinterpret_cast<u16x4*>(outb + (size_t)row * 1024)[tid] = ob;
  } else {
    if (res) {
      const float4 rv = reinterpret_cast<const float4*>(res + (size_t)row * 1024)[tid];
      o4.x += rv.x; o4.y += rv.y; o4.z += rv.z; o4.w += rv.w;
    }
    reinterpret_cast<float4*>(out + (size_t)row * 1024)[tid] = o4;
  }
}

// ---------------------------------------------------------------- bf16 GEMM, 2-phase pipelined (round-8 proven)
// C[M][N] = act(A[M][K] @ B[N][K]^T + bias) + res ; tiles 128x128, BK=32
// 1D grid = (M/128)*gy with bijective XCD-chunked swizzle; gy = N/128.
__global__ __launch_bounds__(256) void gemm_bf16_kernel(
    const unsigned short* __restrict__ A, int lda,
    const unsigned short* __restrict__ B, int ldb,
    void* __restrict__ Cv, int ldc,
    const float* __restrict__ bias, const float* __restrict__ res,
    int K, int act, int outbf, int gy)
{
  __shared__ unsigned short As[2][128 * 32];
  __shared__ unsigned short Bs[2][128 * 32];
  const int t = threadIdx.x;
  const int w = t >> 6, l = t & 63;

  const int q = gridDim.x >> 3;
  const int nid = (blockIdx.x & 7) * q + (blockIdx.x >> 3);
  const int bm = (nid / gy) * 128;
  const int bn = (nid % gy) * 128;

  const int wr = (w >> 1) * 64, wc = (w & 1) * 64;
  f32x4 acc[4][4] = {};

  const int srow = t >> 2;          // 0..63
  const int sk = (t & 3) * 8;
  const unsigned short* gA0 = A + (size_t)(bm + srow) * lda + sk;
  const unsigned short* gA1 = gA0 + (size_t)64 * lda;
  const unsigned short* gB0 = B + (size_t)(bn + srow) * ldb + sk;
  const unsigned short* gB1 = gB0 + (size_t)64 * ldb;

  const int fr = l & 15;
  const int kb = (l >> 4) * 8;

#define STAGE(buf, k0) do { \
    GLDS(gA0 + (k0), &As[buf][w * 512]); \
    GLDS(gA1 + (k0), &As[buf][2048 + w * 512]); \
    GLDS(gB0 + (k0), &Bs[buf][w * 512]); \
    GLDS(gB1 + (k0), &Bs[buf][2048 + w * 512]); \
  } while (0)

#define COMPUTE(buf) do { \
    bf16x8 af[4], bfr[4]; \
    _Pragma("unroll") \
    for (int i = 0; i < 4; ++i) \
      af[i] = *reinterpret_cast<const bf16x8*>(&As[buf][(wr + i * 16 + fr) * 32 + kb]); \
    _Pragma("unroll") \
    for (int j = 0; j < 4; ++j) \
      bfr[j] = *reinterpret_cast<const bf16x8*>(&Bs[buf][(wc + j * 16 + fr) * 32 + kb]); \
    _Pragma("unroll") \
    for (int i = 0; i < 4; ++i) \
      _Pragma("unroll") \
      for (int j = 0; j < 4; ++j) \
        acc[i][j] = __builtin_amdgcn_mfma_f32_16x16x32_bf16(af[i], bfr[j], acc[i][j], 0, 0, 0); \
  } while (0)

  STAGE(0, 0);
  DRAIN_VM();
  __syncthreads();
  int cur = 0;
  for (int k0 = 32; k0 < K; k0 += 32) {
    __builtin_amdgcn_sched_barrier(0);
    STAGE(cur ^ 1, k0);
    __builtin_amdgcn_sched_barrier(0);
    COMPUTE(cur);
    DRAIN_VM();
    __syncthreads();
    cur ^= 1;
  }
  COMPUTE(cur);
#undef STAGE
#undef COMPUTE

  const int crow = (l >> 4) * 4;
  const int ccol = l & 15;
  float* Cf = (float*)Cv;
  unsigned short* Cb = (unsigned short*)Cv;
#pragma unroll
  for (int i = 0; i < 4; ++i) {
#pragma unroll
    for (int j = 0; j < 4; ++j) {
      const int n = bn + wc + j * 16 + ccol;
      const float bv = bias ? bias[n] : 0.f;
#pragma unroll
      for (int r = 0; r < 4; ++r) {
        const int m = bm + wr + i * 16 + crow + r;
        float v = acc[i][j][r] + bv;
        if (act == 1) v = (v > 20.f) ? v : __logf(1.f + __expf(v));
        else if (act == 2) v = (v >= 0.f) ? v : 0.01f * v;
        if (res) v += res[(size_t)m * ldc + n];
        if (outbf) Cb[(size_t)m * ldc + n] = f2bf(v);
        else       Cf[(size_t)m * ldc + n] = v;
      }
    }
  }
}

// ---------------------------------------------------------------- bf16 GEMM, intra-block K-split, BK templated
// 512 threads = 2 groups x 4 waves; group g does K-half with its own LDS dbuf.
// BK=32: LDS 64KB; BK=64: LDS 128KB (gfx950 allows up to 160KB/workgroup).
// Reduction: group 1 stores acc to LDS (reused), group 0 adds + epilogue.
template<int BK>
__global__ __launch_bounds__(512) void gemm_ksplit_kernel(
    const unsigned short* __restrict__ A, int lda,
    const unsigned short* __restrict__ B, int ldb,
    void* __restrict__ Cv, int ldc,
    const float* __restrict__ bias, const float* __restrict__ res,
    int K, int act, int outbf, int gy)
{
  constexpr int ABYTES = 128 * BK * 2;            // one buffer, one group
  constexpr int NISS = (BK == 32) ? 2 : 4;        // GLDS issues per matrix
  constexpr int RPI  = (BK == 32) ? 64 : 32;      // rows per issue
  constexpr int NS   = BK / 32;                   // k-subtiles per step
  __shared__ __align__(16) unsigned char smem[8 * ABYTES];
  const int tid = threadIdx.x;
  const int grp = tid >> 8;         // 0 or 1
  const int t = tid & 255;
  const int w = t >> 6, l = t & 63;

  const int q = gridDim.x >> 3;
  const int nid = (blockIdx.x & 7) * q + (blockIdx.x >> 3);
  const int bm = (nid / gy) * 128;
  const int bn = (nid % gy) * 128;

  const int K2 = K >> 1;
  const int koff = grp * K2;
  const int wr = (w >> 1) * 64, wc = (w & 1) * 64;
  f32x4 acc[4][4] = {};

  const int srow = (BK == 32) ? (t >> 2) : (t >> 3);
  const int sk   = (BK == 32) ? ((t & 3) * 8) : ((t & 7) * 8);
  const unsigned short* gA = A + (size_t)(bm + srow) * lda + koff + sk;
  const unsigned short* gB = B + (size_t)(bn + srow) * ldb + koff + sk;

  const int gbase = grp * 2 * ABYTES;
  const int fr = l & 15;
  const int kb = (l >> 4) * 8;

#define SAb(buf) (smem + gbase + (buf) * ABYTES)
#define SBb(buf) (smem + 4 * ABYTES + gbase + (buf) * ABYTES)

#define STAGEK(buf, k0) do { \
    _Pragma("unroll") \
    for (int ii = 0; ii < NISS; ++ii) { \
      GLDS(gA + (k0) + (size_t)ii * RPI * lda, SAb(buf) + ii * 4096 + w * 1024); \
      GLDS(gB + (k0) + (size_t)ii * RPI * ldb, SBb(buf) + ii * 4096 + w * 1024); \
    } \
  } while (0)

#define COMPUTEK(buf) do { \
    _Pragma("unroll") \
    for (int s = 0; s < NS; ++s) { \
      bf16x8 af[4], bfr[4]; \
      _Pragma("unroll") \
      for (int i = 0; i < 4; ++i) \
        af[i] = *reinterpret_cast<const bf16x8*>((const unsigned short*)SAb(buf) + (wr + i * 16 + fr) * BK + s * 32 + kb); \
      _Pragma("unroll") \
      for (int j = 0; j < 4; ++j) \
        bfr[j] = *reinterpret_cast<const bf16x8*>((const unsigned short*)SBb(buf) + (wc + j * 16 + fr) * BK + s * 32 + kb); \
      _Pragma("unroll") \
      for (int i = 0; i < 4; ++i) \
        _Pragma("unroll") \
        for (int j = 0; j < 4; ++j) \
          acc[i][j] = __builtin_amdgcn_mfma_f32_16x16x32_bf16(af[i], bfr[j], acc[i][j], 0, 0, 0); \
    } \
  } while (0)

  STAGEK(0, 0);
  DRAIN_VM();
  __syncthreads();
  int cur = 0;
  for (int k0 = BK; k0 < K2; k0 += BK) {
    __builtin_amdgcn_sched_barrier(0);
    STAGEK(cur ^ 1, k0);
    __builtin_amdgcn_sched_barrier(0);
    COMPUTEK(cur);
    DRAIN_VM();
    __syncthreads();
    cur ^= 1;
  }
  COMPUTEK(cur);
#undef STAGEK
#undef COMPUTEK
#undef SAb
#undef SBb

  // cross-group reduction: first 64KB of smem reused as f32 buffer
  __syncthreads();                       // all staging reads complete
  float* red = (float*)smem;             // 256 threads x 64 floats
  if (grp) {
#pragma unroll
    for (int i = 0; i < 4; ++i)
#pragma unroll
      for (int j = 0; j < 4; ++j)
        *reinterpret_cast<f32x4*>(&red[(t << 6) + (i * 4 + j) * 4]) = acc[i][j];
  }
  __syncthreads();
  if (!grp) {
    const int crow = (l >> 4) * 4;
    const int ccol = l & 15;
    float* Cf = (float*)Cv;
    unsigned short* Cb = (unsigned short*)Cv;
#pragma unroll
    for (int i = 0; i < 4; ++i) {
#pragma unroll
      for (int j = 0; j < 4; ++j) {
        const f32x4 o = *reinterpret_cast<const f32x4*>(&red[(t << 6) + (i * 4 + j) * 4]);
        const int n = bn + wc + j * 16 + ccol;
        const float bv = bias ? bias[n] : 0.f;
#pragma unroll
        for (int r = 0; r < 4; ++r) {
          const int m = bm + wr + i * 16 + crow + r;
          float v = acc[i][j][r] + o[r] + bv;
          if (act == 1) v = (v > 20.f) ? v : __logf(1.f + __expf(v));
          else if (act == 2) v = (v >= 0.f) ? v : 0.01f * v;
          if (res) v += res[(size_t)m * ldc + n];
          if (outbf) Cb[(size_t)m * ldc + n] = f2bf(v);
          else       Cf[(size_t)m * ldc + n] = v;
        }
      }
    }
  }
}

// ---------------------------------------------------------------- x_proj split-K (N=96), 2-phase (proven)
__global__ __launch_bounds__(256) void xproj_kernel(
    const unsigned short* __restrict__ A, int lda,
    const unsigned short* __restrict__ B, int ldb,
    float* __restrict__ C)
{
  __shared__ unsigned short As[2][128 * 32];
  __shared__ unsigned short Bs[2][96 * 32];
  const int t = threadIdx.x;
  const int w = t >> 6, l = t & 63;
  const int bm = blockIdx.x * 128;
  const int kbase = blockIdx.y * 128;

  f32x4 acc[2][6] = {};

  const int srow = t >> 2;
  const int sk = (t & 3) * 8;
  const unsigned short* gA0 = A + (size_t)(bm + srow) * lda + kbase + sk;
  const unsigned short* gA1 = gA0 + (size_t)64 * lda;
  const unsigned short* gB0 = B + (size_t)srow * ldb + kbase + sk;
  const unsigned short* gB1 = gB0 + (size_t)64 * ldb;

  const int fr = l & 15;
  const int kb = (l >> 4) * 8;

#define STAGEX(buf, k0) do { \
    GLDS(gA0 + (k0), &As[buf][w * 512]); \
    GLDS(gA1 + (k0), &As[buf][2048 + w * 512]); \
    GLDS(gB0 + (k0), &Bs[buf][w * 512]); \
    if (w < 2) GLDS(gB1 + (k0), &Bs[buf][2048 + w * 512]); \
  } while (0)

#define COMPUTEX(buf) do { \
    bf16x8 af[2], bfr[6]; \
    _Pragma("unroll") \
    for (int i = 0; i < 2; ++i) \
      af[i] = *reinterpret_cast<const bf16x8*>(&As[buf][(w * 32 + i * 16 + fr) * 32 + kb]); \
    _Pragma("unroll") \
    for (int j = 0; j < 6; ++j) \
      bfr[j] = *reinterpret_cast<const bf16x8*>(&Bs[buf][(j * 16 + fr) * 32 + kb]); \
    _Pragma("unroll") \
    for (int i = 0; i < 2; ++i) \
      _Pragma("unroll") \
      for (int j = 0; j < 6; ++j) \
        acc[i][j] = __builtin_amdgcn_mfma_f32_16x16x32_bf16(af[i], bfr[j], acc[i][j], 0, 0, 0); \
  } while (0)

  STAGEX(0, 0);
  DRAIN_VM();
  __syncthreads();
  int cur = 0;
  for (int s = 1; s < 4; ++s) {
    __builtin_amdgcn_sched_barrier(0);
    STAGEX(cur ^ 1, s * 32);
    __builtin_amdgcn_sched_barrier(0);
    COMPUTEX(cur);
    DRAIN_VM();
    __syncthreads();
    cur ^= 1;
  }
  COMPUTEX(cur);
#undef STAGEX
#undef COMPUTEX

  const int crow = (l >> 4) * 4;
  const int ccol = l & 15;
#pragma unroll
  for (int i = 0; i < 2; ++i)
#pragma unroll
    for (int j = 0; j < 6; ++j)
#pragma unroll
      for (int r = 0; r < 4; ++r) {
        const int m = bm + w * 32 + i * 16 + crow + r;
        const int n = j * 16 + ccol;
        atomicAdd(&C[(size_t)m * 96 + n], acc[i][j][r]);
      }
}

// ---------------------------------------------------------------- conv(k=2)+SiLU (bf16 xz)
__global__ __launch_bounds__(256) void conv_silu_kernel(
    const unsigned short* __restrict__ xz, const float* __restrict__ cw,
    const float* __restrict__ cb, float* __restrict__ xc,
    unsigned short* __restrict__ xcb)
{
  const int idx = blockIdx.x * 256 + threadIdx.x;   // over 4096*1024
  const int row = idx >> 10;
  const int d = idx & 1023;
  const int l = row & (L_SEQ - 1);
  const float cur = bf2f(xz[(size_t)row * 2048 + d]);
  const float prev = (l == 0) ? 0.f : bf2f(xz[(size_t)(row - 1) * 2048 + d]);
  const float v = prev * cw[d * 2 + 0] + cur * cw[d * 2 + 1] + cb[d];
  const float sv = v / (1.f + __expf(-v));
  xc[idx] = sv;
  xcb[idx] = f2bf(sv);
}

// ---------------------------------------------------------------- scan pass 1
__global__ __launch_bounds__(256) void scan_pass1(
    const float* __restrict__ delta, const float* __restrict__ xc,
    const float* __restrict__ xdbl, const float* __restrict__ A_log,
    float* __restrict__ hfin, float* __restrict__ pcum)
{
  const int tid = threadIdx.x;
  const int db = blockIdx.x & 3;
  const int c = (blockIdx.x >> 2) & (NCHUNK - 1);
  const int b = blockIdx.x >> 7;
  const int d = db * 256 + tid;
  __shared__ float Bsh[CH][16];
  {
    const int lr = tid >> 2, q = tid & 3;
    const float* p = xdbl + ((size_t)(b * L_SEQ + c * CH + lr) * 96) + 64 + q * 4;
    *reinterpret_cast<float4*>(&Bsh[lr][q * 4]) = *reinterpret_cast<const float4*>(p);
  }
  float a[NSTATE];
#pragma unroll
  for (int n = 0; n < NSTATE; ++n) a[n] = -__expf(A_log[d * 16 + n]);
  __syncthreads();
  float h[NSTATE], P[NSTATE];
#pragma unroll
  for (int n = 0; n < NSTATE; ++n) { h[n] = 0.f; P[n] = 1.f; }
  const size_t rowbase = (size_t)(b * L_SEQ + c * CH);
  for (int s = 0; s < CH; ++s) {
    const size_t row = rowbase + s;
    const float dl = delta[row * 1024 + d];
    const float xcv = xc[row * 1024 + d];
#pragma unroll
    for (int n = 0; n < NSTATE; ++n) {
      const float dA = __expf(dl * a[n]);
      h[n] = h[n] * dA + (dl * Bsh[s][n]) * xcv;
      P[n] *= dA;
    }
  }
  const size_t base = ((size_t)((b * NCHUNK + c) * 1024 + d)) * 16;
  float4* hp = reinterpret_cast<float4*>(hfin + base);
  float4* pp = reinterpret_cast<float4*>(pcum + base);
#pragma unroll
  for (int qq = 0; qq < 4; ++qq) {
    hp[qq] = make_float4(h[qq * 4], h[qq * 4 + 1], h[qq * 4 + 2], h[qq * 4 + 3]);
    pp[qq] = make_float4(P[qq * 4], P[qq * 4 + 1], P[qq * 4 + 2], P[qq * 4 + 3]);
  }
}

// ---------------------------------------------------------------- scan pass 2
__global__ __launch_bounds__(256) void scan_pass2(
    const float* __restrict__ hfin, const float* __restrict__ pcum,
    float* __restrict__ hstart)
{
  const int t = blockIdx.x * 256 + threadIdx.x;
  const int b = t >> 14;
  const int dn = t & 16383;
  const size_t base = (size_t)b * NCHUNK * 16384 + dn;
  float h = 0.f;
  for (int c = 0; c < NCHUNK; ++c) {
    const size_t idx = base + (size_t)c * 16384;
    hstart[idx] = h;
    h = pcum[idx] * h + hfin[idx];
  }
}

// ---------------------------------------------------------------- scan pass 3 (bf16 y out, bf16 z in)
__global__ __launch_bounds__(256) void scan_pass3(
    const float* __restrict__ delta, const float* __restrict__ xc,
    const float* __restrict__ xdbl, const float* __restrict__ A_log,
    const float* __restrict__ hstart, const float* __restrict__ Dp,
    const unsigned short* __restrict__ xz, unsigned short* __restrict__ yout)
{
  const int tid = threadIdx.x;
  const int db = blockIdx.x & 3;
  const int c = (blockIdx.x >> 2) & (NCHUNK - 1);
  const int b = blockIdx.x >> 7;
  const int d = db * 256 + tid;
  __shared__ float Bsh[CH][16];
  __shared__ float Csh[CH][16];
  {
    const int lr = tid >> 2, q = tid & 3;
    const float* p = xdbl + ((size_t)(b * L_SEQ + c * CH + lr) * 96);
    *reinterpret_cast<float4*>(&Bsh[lr][q * 4]) = *reinterpret_cast<const float4*>(p + 64 + q * 4);
    *reinterpret_cast<float4*>(&Csh[lr][q * 4]) = *reinterpret_cast<const float4*>(p + 80 + q * 4);
  }
  float a[NSTATE];
#pragma unroll
  for (int n = 0; n < NSTATE; ++n) a[n] = -__expf(A_log[d * 16 + n]);
  float h[NSTATE];
  {
    const size_t base = ((size_t)((b * NCHUNK + c) * 1024 + d)) * 16;
    const float4* hp = reinterpret_cast<const float4*>(hstart + base);
#pragma unroll
    for (int qq = 0; qq < 4; ++qq) {
      const float4 v = hp[qq];
      h[qq * 4] = v.x; h[qq * 4 + 1] = v.y; h[qq * 4 + 2] = v.z; h[qq * 4 + 3] = v.w;
    }
  }
  const float dpv = Dp[d];
  __syncthreads();
  const size_t rowbase = (size_t)(b * L_SEQ + c * CH);
  for (int s = 0; s < CH; ++s) {
    const size_t row = rowbase + s;
    const float dl = delta[row * 1024 + d];
    const float xcv = xc[row * 1024 + d];
    float y = 0.f;
#pragma unroll
    for (int n = 0; n < NSTATE; ++n) {
      const float dA = __expf(dl * a[n]);
      h[n] = h[n] * dA + (dl * Bsh[s][n]) * xcv;
      y += h[n] * Csh[s][n];
    }
    const float z = bf2f(xz[row * 2048 + 1024 + d]);
    const float sil = z / (1.f + __expf(-z));
    yout[row * 1024 + d] = f2bf((y + xcv * dpv) * sil);
  }
}

// ---------------------------------------------------------------- launch
extern "C" void kernel_launch(void* const* d_in, const int* in_sizes, int n_in,
                              void* d_out, int out_size, void* d_ws, size_t ws_size,
                              hipStream_t stream)
{
  (void)in_sizes; (void)n_in; (void)out_size; (void)ws_size;
  const float* src        = (const float*)d_in[0];
  const float* in_proj_w  = (const float*)d_in[1];
  const float* conv_w     = (const float*)d_in[2];
  const float* conv_b     = (const float*)d_in[3];
  const float* x_proj_w   = (const float*)d_in[4];
  const float* dt_proj_w  = (const float*)d_in[5];
  const float* dt_proj_b  = (const float*)d_in[6];
  const float* A_log      = (const float*)d_in[7];
  const float* Dp         = (const float*)d_in[8];
  const float* out_proj_w = (const float*)d_in[9];
  const float* mnorm_g    = (const float*)d_in[10];
  const float* mnorm_b    = (const float*)d_in[11];
  const float* n1_g       = (const float*)d_in[12];
  const float* n1_b       = (const float*)d_in[13];
  const float* n2_g       = (const float*)d_in[14];
  const float* n2_b       = (const float*)d_in[15];
  const float* n3_g       = (const float*)d_in[16];
  const float* n3_b       = (const float*)d_in[17];
  const float* ffn_w1     = (const float*)d_in[18];
  const float* ffn_w2     = (const float*)d_in[19];
  const float* fe_w       = (const float*)d_in[20];
  const float* fe_b       = (const float*)d_in[21];
  float* out = (float*)d_out;
  float* ws  = (float*)d_ws;

  // ---- workspace layout (float offsets; ranges disjoint — audited round 6) ----
  unsigned short* xzb  = (unsigned short*)ws;               // u16[0 .. 8388608)   = f[0 .. 4194304)
  unsigned short* xdblb= (unsigned short*)(ws + 4194304);   // u16 393216          = f[4194304 .. 4390912)
  unsigned short* dtwb = (unsigned short*)(ws + 4390912);   // u16 65536           = f[4390912 .. 4423680)
  float* xc    = ws + 8388608;        // f[ 8388608 .. 12582912)
  float* xdbl  = ws + 12582912;       // f[12582912 .. 12976128), slot to 13107200
  float* delta = ws + 13107200;       // f[13107200 .. 17301504)
  float* s5    = ws + 17301504;       // f[17301504 .. 21495808)
  float* src1  = ws + 21495808;       // f[21495808 .. 25690112)
  float* hfin  = ws + 25690112;       // f[25690112 .. 26738688)
  float* pcum  = ws + 26738688;       // f[26738688 .. 27787264)
  float* hst   = ws + 27787264;       // f[27787264 .. 28835840)
  unsigned short* s1b  = (unsigned short*)(ws + 28835840);  // u16 4194304 = f[.. 30932992)
  unsigned short* xcb  = (unsigned short*)(ws + 30932992);  // u16 4194304 = f[.. 33030144)
  unsigned short* yb   = (unsigned short*)(ws + 33030144);  // u16 4194304 = f[.. 35127296)
  unsigned short* f1b  = (unsigned short*)(ws + 35127296);  // u16 16777216 = f[.. 43515904)
  unsigned short* ipwb = (unsigned short*)(ws + 43515904);  // u16 2097152 = f[.. 44564480)
  unsigned short* xpwb = (unsigned short*)(ws + 44564480);  // u16 98304   = f[.. 44613632)
  unsigned short* opwb = (unsigned short*)(ws + 44613632);  // u16 1048576 = f[.. 45137920)
  unsigned short* w1b  = (unsigned short*)(ws + 45137920);  // u16 4194304 = f[.. 47235072)
  unsigned short* w2b  = (unsigned short*)(ws + 47235072);  // u16 4194304 = f[.. 49332224)
  unsigned short* fewb = (unsigned short*)(ws + 49332224);  // u16 1048576 = f[.. 49856512)

  const dim3 blk(256);
  const dim3 blk512(512);

  // 0. all weights -> bf16 (single launch; 3186688 float4s)
  cvt_all_kernel<<<12448, blk, 0, stream>>>(
      in_proj_w, x_proj_w, dt_proj_w, out_proj_w, ffn_w1, ffn_w2, fe_w,
      ipwb, xpwb, dtwb, opwb, w1b, w2b, fewb);

  // 1. x1 = LN(src; n1) -> bf16
  ln_kernel<<<NROWS, blk, 0, stream>>>(src, n1_g, n1_b, nullptr, nullptr, s1b);
  // 2. xz = x1 @ in_proj_w^T -> bf16  (4096x2048x1024, ksplit BK=32, 2 blocks/CU)
  gemm_ksplit_kernel<32><<<512, blk512, 0, stream>>>(s1b, 1024, ipwb, 1024, xzb, 2048,
                                                     nullptr, nullptr, 1024, 0, 1, 16);
  // 3. x_c = silu(conv(x_in))  -> f32 + bf16
  conv_silu_kernel<<<16384, blk, 0, stream>>>(xzb, conv_w, conv_b, xc, xcb);
  // 4. x_dbl = x_c @ x_proj_w^T  (split-K=8, atomic f32)
  hipMemsetAsync(xdbl, 0, (size_t)NROWS * 96 * sizeof(float), stream);
  xproj_kernel<<<dim3(32, 8), blk, 0, stream>>>(xcb, 1024, xpwb, 1024, xdbl);
  // 4b. xdbl -> bf16 for dt_proj
  cvt_bf16_kernel<<<384, blk, 0, stream>>>(xdbl, xdblb, 98304);
  // 5. delta = softplus(dt @ dt_proj_w^T + b)  (4096x1024x64)
  gemm_bf16_kernel<<<256, blk, 0, stream>>>(xdblb, 96, dtwb, 64, delta, 1024,
                                            dt_proj_b, nullptr, 64, 1, 0, 8);
  // 6-8. selective scan
  scan_pass1<<<256, blk, 0, stream>>>(delta, xc, xdbl, A_log, hfin, pcum);
  scan_pass2<<<128, blk, 0, stream>>>(hfin, pcum, hst);
  scan_pass3<<<256, blk, 0, stream>>>(delta, xc, xdbl, A_log, hst, Dp, xzb, yb);
  // 9. mamba_out = y @ out_proj_w^T  (4096x1024x1024, ksplit BK=64)
  gemm_ksplit_kernel<64><<<256, blk512, 0, stream>>>(yb, 1024, opwb, 1024, s5, 1024,
                                                     nullptr, nullptr, 1024, 0, 0, 8);
  // 10. src1 = src + LN(mamba_out; mnorm)
  ln_kernel<<<NROWS, blk, 0, stream>>>(s5, mnorm_g, mnorm_b, src, src1, nullptr);
  // 11. x2 = LN(src1; n2) -> bf16
  ln_kernel<<<NROWS, blk, 0, stream>>>(src1, n2_g, n2_b, nullptr, nullptr, s1b);
  // 12. f1 = leaky(x2 @ ffn_w1^T) -> bf16  (4096x4096x1024)
  gemm_bf16_kernel<<<1024, blk, 0, stream>>>(s1b, 1024, w1b, 1024, f1b, 4096,
                                             nullptr, nullptr, 1024, 2, 1, 32);
  // 13. src2 = src1 + f1 @ ffn_w2^T  (4096x1024x4096, ksplit BK=64)
  gemm_ksplit_kernel<64><<<256, blk512, 0, stream>>>(f1b, 4096, w2b, 4096, s5, 1024,
                                                     nullptr, src1, 4096, 0, 0, 8);
  // 14. x3 = LN(src2; n3) -> bf16
  ln_kernel<<<NROWS, blk, 0, stream>>>(s5, n3_g, n3_b, nullptr, nullptr, s1b);
  // 15. out = src2 + x3 @ fe_w^T + fe_b  (4096x1024x1024, ksplit BK=64)
  gemm_ksplit_kernel<64><<<256, blk512, 0, stream>>>(s1b, 1024, fewb, 1024, out, 1024,
                                                     fe_b, s5, 1024, 0, 0, 8);
}

// Round 16
// 397.532 us; speedup vs baseline: 1.2337x; 1.0225x over previous
//
#include <hip/hip_runtime.h>
#include <hip/hip_bf16.h>
#include <cstddef>

#define L_SEQ   2048
#define NBATCH  2
#define NROWS   (NBATCH * L_SEQ)   /* 4096 */
#define NSTATE  16
#define CH      64
#define NCHUNK  (L_SEQ / CH)       /* 32 */

typedef __bf16 bf16x8 __attribute__((ext_vector_type(8)));
typedef float  f32x4  __attribute__((ext_vector_type(4)));
typedef unsigned short u16x4 __attribute__((ext_vector_type(4)));

static __device__ __forceinline__ unsigned short f2bf(float f) {
  unsigned int x = __builtin_bit_cast(unsigned int, f);
  x += 0x7fffu + ((x >> 16) & 1u);          // RNE
  return (unsigned short)(x >> 16);
}
static __device__ __forceinline__ float bf2f(unsigned short u) {
  return __builtin_bit_cast(float, ((unsigned int)u) << 16);
}

// async global->LDS, 16B per lane; LDS dest = wave-uniform base + lane*16
#define GLDS(g, l) __builtin_amdgcn_global_load_lds( \
    (const __attribute__((address_space(1))) void*)(g), \
    (__attribute__((address_space(3))) void*)(l), 16, 0, 0)

#define DRAIN_VM() asm volatile("s_waitcnt vmcnt(0)" ::: "memory")

// ---------------------------------------------------------------- f32 -> bf16 (generic, for xdbl)
__global__ __launch_bounds__(256) void cvt_bf16_kernel(
    const float* __restrict__ in, unsigned short* __restrict__ out, int n4)
{
  const int i = blockIdx.x * 256 + threadIdx.x;
  if (i < n4) {
    const float4 v = reinterpret_cast<const float4*>(in)[i];
    u16x4 o;
    o[0] = f2bf(v.x); o[1] = f2bf(v.y); o[2] = f2bf(v.z); o[3] = f2bf(v.w);
    reinterpret_cast<u16x4*>(out)[i] = o;
  }
}

// ---------------------------------------------------------------- all weights -> bf16, one launch
__global__ __launch_bounds__(256) void cvt_all_kernel(
    const float* __restrict__ ipw, const float* __restrict__ xpw,
    const float* __restrict__ dtw, const float* __restrict__ opw,
    const float* __restrict__ w1,  const float* __restrict__ w2,
    const float* __restrict__ few,
    unsigned short* __restrict__ o_ipw, unsigned short* __restrict__ o_xpw,
    unsigned short* __restrict__ o_dtw, unsigned short* __restrict__ o_opw,
    unsigned short* __restrict__ o_w1,  unsigned short* __restrict__ o_w2,
    unsigned short* __restrict__ o_few)
{
  int i = blockIdx.x * 256 + threadIdx.x;
  const float* src; unsigned short* dst;
  if (i < 524288)                 { src = ipw; dst = o_ipw; }
  else if ((i -= 524288) < 24576) { src = xpw; dst = o_xpw; }
  else if ((i -= 24576) < 16384)  { src = dtw; dst = o_dtw; }
  else if ((i -= 16384) < 262144) { src = opw; dst = o_opw; }
  else if ((i -= 262144) < 1048576){ src = w1; dst = o_w1; }
  else if ((i -= 1048576) < 1048576){ src = w2; dst = o_w2; }
  else if ((i -= 1048576) < 262144){ src = few; dst = o_few; }
  else return;
  const float4 v = reinterpret_cast<const float4*>(src)[i];
  u16x4 o;
  o[0] = f2bf(v.x); o[1] = f2bf(v.y); o[2] = f2bf(v.z); o[3] = f2bf(v.w);
  reinterpret_cast<u16x4*>(dst)[i] = o;
}

// ---------------------------------------------------------------- LayerNorm
__global__ __launch_bounds__(256) void ln_kernel(
    const float* __restrict__ in, const float* __restrict__ g,
    const float* __restrict__ bta, const float* __restrict__ res,
    float* __restrict__ out, unsigned short* __restrict__ outb)
{
  const int row = blockIdx.x;
  const int tid = threadIdx.x;
  __shared__ float sm[8];
  const float4 v = reinterpret_cast<const float4*>(in + (size_t)row * 1024)[tid];
  float s = v.x + v.y + v.z + v.w;
#pragma unroll
  for (int o = 32; o > 0; o >>= 1) s += __shfl_down(s, o, 64);
  if ((tid & 63) == 0) sm[tid >> 6] = s;
  __syncthreads();
  const float mean = (sm[0] + sm[1] + sm[2] + sm[3]) * (1.f / 1024.f);
  const float dx = v.x - mean, dy = v.y - mean, dz = v.z - mean, dw = v.w - mean;
  float q = dx * dx + dy * dy + dz * dz + dw * dw;
#pragma unroll
  for (int o = 32; o > 0; o >>= 1) q += __shfl_down(q, o, 64);
  __syncthreads();
  if ((tid & 63) == 0) sm[tid >> 6] = q;
  __syncthreads();
  const float var = (sm[0] + sm[1] + sm[2] + sm[3]) * (1.f / 1024.f);
  const float rstd = rsqrtf(var + 1e-5f);
  const float4 gv = reinterpret_cast<const float4*>(g)[tid];
  const float4 bv = reinterpret_cast<const float4*>(bta)[tid];
  float4 o4;
  o4.x = dx * rstd * gv.x + bv.x;
  o4.y = dy * rstd * gv.y + bv.y;
  o4.z = dz * rstd * gv.z + bv.z;
  o4.w = dw * rstd * gv.w + bv.w;
  if (outb) {
    u16x4 ob;
    ob[0] = f2bf(o4.x); ob[1] = f2bf(o4.y); ob[2] = f2bf(o4.z); ob[3] = f2bf(o4.w);
    reinterpret_cast<u16x4*>(outb + (size_t)row * 1024)[tid] = ob;
  } else {
    if (res) {
      const float4 rv = reinterpret_cast<const float4*>(res + (size_t)row * 1024)[tid];
      o4.x += rv.x; o4.y += rv.y; o4.z += rv.z; o4.w += rv.w;
    }
    reinterpret_cast<float4*>(out + (size_t)row * 1024)[tid] = o4;
  }
}

// ---------------------------------------------------------------- bf16 GEMM, 2-phase pipelined (round-8 proven)
// C[M][N] = act(A[M][K] @ B[N][K]^T + bias) + res ; tiles 128x128, BK=32
// 1D grid = (M/128)*gy with bijective XCD-chunked swizzle; gy = N/128.
__global__ __launch_bounds__(256) void gemm_bf16_kernel(
    const unsigned short* __restrict__ A, int lda,
    const unsigned short* __restrict__ B, int ldb,
    void* __restrict__ Cv, int ldc,
    const float* __restrict__ bias, const float* __restrict__ res,
    int K, int act, int outbf, int gy)
{
  __shared__ unsigned short As[2][128 * 32];
  __shared__ unsigned short Bs[2][128 * 32];
  const int t = threadIdx.x;
  const int w = t >> 6, l = t & 63;

  const int q = gridDim.x >> 3;
  const int nid = (blockIdx.x & 7) * q + (blockIdx.x >> 3);
  const int bm = (nid / gy) * 128;
  const int bn = (nid % gy) * 128;

  const int wr = (w >> 1) * 64, wc = (w & 1) * 64;
  f32x4 acc[4][4] = {};

  const int srow = t >> 2;          // 0..63
  const int sk = (t & 3) * 8;
  const unsigned short* gA0 = A + (size_t)(bm + srow) * lda + sk;
  const unsigned short* gA1 = gA0 + (size_t)64 * lda;
  const unsigned short* gB0 = B + (size_t)(bn + srow) * ldb + sk;
  const unsigned short* gB1 = gB0 + (size_t)64 * ldb;

  const int fr = l & 15;
  const int kb = (l >> 4) * 8;

#define STAGE(buf, k0) do { \
    GLDS(gA0 + (k0), &As[buf][w * 512]); \
    GLDS(gA1 + (k0), &As[buf][2048 + w * 512]); \
    GLDS(gB0 + (k0), &Bs[buf][w * 512]); \
    GLDS(gB1 + (k0), &Bs[buf][2048 + w * 512]); \
  } while (0)

#define COMPUTE(buf) do { \
    bf16x8 af[4], bfr[4]; \
    _Pragma("unroll") \
    for (int i = 0; i < 4; ++i) \
      af[i] = *reinterpret_cast<const bf16x8*>(&As[buf][(wr + i * 16 + fr) * 32 + kb]); \
    _Pragma("unroll") \
    for (int j = 0; j < 4; ++j) \
      bfr[j] = *reinterpret_cast<const bf16x8*>(&Bs[buf][(wc + j * 16 + fr) * 32 + kb]); \
    _Pragma("unroll") \
    for (int i = 0; i < 4; ++i) \
      _Pragma("unroll") \
      for (int j = 0; j < 4; ++j) \
        acc[i][j] = __builtin_amdgcn_mfma_f32_16x16x32_bf16(af[i], bfr[j], acc[i][j], 0, 0, 0); \
  } while (0)

  STAGE(0, 0);
  DRAIN_VM();
  __syncthreads();
  int cur = 0;
  for (int k0 = 32; k0 < K; k0 += 32) {
    __builtin_amdgcn_sched_barrier(0);
    STAGE(cur ^ 1, k0);
    __builtin_amdgcn_sched_barrier(0);
    COMPUTE(cur);
    DRAIN_VM();
    __syncthreads();
    cur ^= 1;
  }
  COMPUTE(cur);
#undef STAGE
#undef COMPUTE

  const int crow = (l >> 4) * 4;
  const int ccol = l & 15;
  float* Cf = (float*)Cv;
  unsigned short* Cb = (unsigned short*)Cv;
#pragma unroll
  for (int i = 0; i < 4; ++i) {
#pragma unroll
    for (int j = 0; j < 4; ++j) {
      const int n = bn + wc + j * 16 + ccol;
      const float bv = bias ? bias[n] : 0.f;
#pragma unroll
      for (int r = 0; r < 4; ++r) {
        const int m = bm + wr + i * 16 + crow + r;
        float v = acc[i][j][r] + bv;
        if (act == 1) v = (v > 20.f) ? v : __logf(1.f + __expf(v));
        else if (act == 2) v = (v >= 0.f) ? v : 0.01f * v;
        if (res) v += res[(size_t)m * ldc + n];
        if (outbf) Cb[(size_t)m * ldc + n] = f2bf(v);
        else       Cf[(size_t)m * ldc + n] = v;
      }
    }
  }
}

// ---------------------------------------------------------------- bf16 GEMM, 256x256 tile, 2-phase, 8 waves
// BM=BN=256, BK=64, 512 threads (2M x 4N waves, per-wave 128x64 out, acc[8][4]).
// LDS = 2 dbuf x (A 32KB + B 32KB) = 128KB static (proven legal via ksplit<64>).
// Per K-step: 512 MFMA/block -> ~620 cyc/SIMD compute phase covers HBM latency
// even at 1 block/CU. Grid = (M/256)*gy, gy = N/256, XCD-chunked swizzle.
__global__ __launch_bounds__(512) void gemm256_kernel(
    const unsigned short* __restrict__ A, int lda,
    const unsigned short* __restrict__ B, int ldb,
    void* __restrict__ Cv, int ldc,
    const float* __restrict__ bias, const float* __restrict__ res,
    int K, int act, int outbf, int gy)
{
  __shared__ __align__(16) unsigned char smem[131072];
  const int t = threadIdx.x;
  const int w = t >> 6, l = t & 63;

  const int q = gridDim.x >> 3;
  const int nid = (blockIdx.x & 7) * q + (blockIdx.x >> 3);
  const int bm = (nid / gy) * 256;
  const int bn = (nid % gy) * 256;

  const int wr = (w >> 2) * 128;    // wave M-offset (2 groups)
  const int wc = (w & 3) * 64;      // wave N-offset (4 groups)
  f32x4 acc[8][4] = {};

  const int srow = t >> 3;          // 0..63
  const int sk8 = (t & 7) * 8;
  const unsigned short* gA = A + (size_t)(bm + srow) * lda + sk8;
  const unsigned short* gB = B + (size_t)(bn + srow) * ldb + sk8;

  const int fr = l & 15;
  const int kb = (l >> 4) * 8;

  // buf layout: A[buf] at smem + buf*32768; B[buf] at smem + 65536 + buf*32768
#define SA6(buf) (smem + (buf) * 32768)
#define SB6(buf) (smem + 65536 + (buf) * 32768)

#define STAGE6(buf, k0) do { \
    _Pragma("unroll") \
    for (int ii = 0; ii < 4; ++ii) { \
      GLDS(gA + (k0) + (size_t)(ii * 64) * lda, SA6(buf) + ii * 8192 + w * 1024); \
      GLDS(gB + (k0) + (size_t)(ii * 64) * ldb, SB6(buf) + ii * 8192 + w * 1024); \
    } \
  } while (0)

#define COMPUTE6(buf) do { \
    _Pragma("unroll") \
    for (int s = 0; s < 2; ++s) { \
      bf16x8 af[8], bfr[4]; \
      _Pragma("unroll") \
      for (int j = 0; j < 4; ++j) \
        bfr[j] = *reinterpret_cast<const bf16x8*>((const unsigned short*)SB6(buf) + (wc + j * 16 + fr) * 64 + s * 32 + kb); \
      _Pragma("unroll") \
      for (int i = 0; i < 8; ++i) \
        af[i] = *reinterpret_cast<const bf16x8*>((const unsigned short*)SA6(buf) + (wr + i * 16 + fr) * 64 + s * 32 + kb); \
      _Pragma("unroll") \
      for (int i = 0; i < 8; ++i) \
        _Pragma("unroll") \
        for (int j = 0; j < 4; ++j) \
          acc[i][j] = __builtin_amdgcn_mfma_f32_16x16x32_bf16(af[i], bfr[j], acc[i][j], 0, 0, 0); \
    } \
  } while (0)

  STAGE6(0, 0);
  DRAIN_VM();
  __syncthreads();
  int cur = 0;
  for (int k0 = 64; k0 < K; k0 += 64) {
    __builtin_amdgcn_sched_barrier(0);
    STAGE6(cur ^ 1, k0);
    __builtin_amdgcn_sched_barrier(0);
    COMPUTE6(cur);
    DRAIN_VM();
    __syncthreads();
    cur ^= 1;
  }
  COMPUTE6(cur);
#undef STAGE6
#undef COMPUTE6
#undef SA6
#undef SB6

  const int crow = (l >> 4) * 4;
  const int ccol = l & 15;
  float* Cf = (float*)Cv;
  unsigned short* Cb = (unsigned short*)Cv;
#pragma unroll
  for (int i = 0; i < 8; ++i) {
#pragma unroll
    for (int j = 0; j < 4; ++j) {
      const int n = bn + wc + j * 16 + ccol;
      const float bv = bias ? bias[n] : 0.f;
#pragma unroll
      for (int r = 0; r < 4; ++r) {
        const int m = bm + wr + i * 16 + crow + r;
        float v = acc[i][j][r] + bv;
        if (act == 1) v = (v > 20.f) ? v : __logf(1.f + __expf(v));
        else if (act == 2) v = (v >= 0.f) ? v : 0.01f * v;
        if (res) v += res[(size_t)m * ldc + n];
        if (outbf) Cb[(size_t)m * ldc + n] = f2bf(v);
        else       Cf[(size_t)m * ldc + n] = v;
      }
    }
  }
}

// ---------------------------------------------------------------- bf16 GEMM, intra-block K-split, BK templated
// 512 threads = 2 groups x 4 waves; group g does K-half with its own LDS dbuf.
// Reduction: group 1 stores acc to LDS (reused), group 0 adds + epilogue.
template<int BK>
__global__ __launch_bounds__(512) void gemm_ksplit_kernel(
    const unsigned short* __restrict__ A, int lda,
    const unsigned short* __restrict__ B, int ldb,
    void* __restrict__ Cv, int ldc,
    const float* __restrict__ bias, const float* __restrict__ res,
    int K, int act, int outbf, int gy)
{
  constexpr int ABYTES = 128 * BK * 2;            // one buffer, one group
  constexpr int NISS = (BK == 32) ? 2 : 4;        // GLDS issues per matrix
  constexpr int RPI  = (BK == 32) ? 64 : 32;      // rows per issue
  constexpr int NS   = BK / 32;                   // k-subtiles per step
  __shared__ __align__(16) unsigned char smem[8 * ABYTES];
  const int tid = threadIdx.x;
  const int grp = tid >> 8;         // 0 or 1
  const int t = tid & 255;
  const int w = t >> 6, l = t & 63;

  const int q = gridDim.x >> 3;
  const int nid = (blockIdx.x & 7) * q + (blockIdx.x >> 3);
  const int bm = (nid / gy) * 128;
  const int bn = (nid % gy) * 128;

  const int K2 = K >> 1;
  const int koff = grp * K2;
  const int wr = (w >> 1) * 64, wc = (w & 1) * 64;
  f32x4 acc[4][4] = {};

  const int srow = (BK == 32) ? (t >> 2) : (t >> 3);
  const int sk   = (BK == 32) ? ((t & 3) * 8) : ((t & 7) * 8);
  const unsigned short* gA = A + (size_t)(bm + srow) * lda + koff + sk;
  const unsigned short* gB = B + (size_t)(bn + srow) * ldb + koff + sk;

  const int gbase = grp * 2 * ABYTES;
  const int fr = l & 15;
  const int kb = (l >> 4) * 8;

#define SAb(buf) (smem + gbase + (buf) * ABYTES)
#define SBb(buf) (smem + 4 * ABYTES + gbase + (buf) * ABYTES)

#define STAGEK(buf, k0) do { \
    _Pragma("unroll") \
    for (int ii = 0; ii < NISS; ++ii) { \
      GLDS(gA + (k0) + (size_t)ii * RPI * lda, SAb(buf) + ii * 4096 + w * 1024); \
      GLDS(gB + (k0) + (size_t)ii * RPI * ldb, SBb(buf) + ii * 4096 + w * 1024); \
    } \
  } while (0)

#define COMPUTEK(buf) do { \
    _Pragma("unroll") \
    for (int s = 0; s < NS; ++s) { \
      bf16x8 af[4], bfr[4]; \
      _Pragma("unroll") \
      for (int i = 0; i < 4; ++i) \
        af[i] = *reinterpret_cast<const bf16x8*>((const unsigned short*)SAb(buf) + (wr + i * 16 + fr) * BK + s * 32 + kb); \
      _Pragma("unroll") \
      for (int j = 0; j < 4; ++j) \
        bfr[j] = *reinterpret_cast<const bf16x8*>((const unsigned short*)SBb(buf) + (wc + j * 16 + fr) * BK + s * 32 + kb); \
      _Pragma("unroll") \
      for (int i = 0; i < 4; ++i) \
        _Pragma("unroll") \
        for (int j = 0; j < 4; ++j) \
          acc[i][j] = __builtin_amdgcn_mfma_f32_16x16x32_bf16(af[i], bfr[j], acc[i][j], 0, 0, 0); \
    } \
  } while (0)

  STAGEK(0, 0);
  DRAIN_VM();
  __syncthreads();
  int cur = 0;
  for (int k0 = BK; k0 < K2; k0 += BK) {
    __builtin_amdgcn_sched_barrier(0);
    STAGEK(cur ^ 1, k0);
    __builtin_amdgcn_sched_barrier(0);
    COMPUTEK(cur);
    DRAIN_VM();
    __syncthreads();
    cur ^= 1;
  }
  COMPUTEK(cur);
#undef STAGEK
#undef COMPUTEK
#undef SAb
#undef SBb

  // cross-group reduction: first 64KB of smem reused as f32 buffer
  __syncthreads();                       // all staging reads complete
  float* red = (float*)smem;             // 256 threads x 64 floats
  if (grp) {
#pragma unroll
    for (int i = 0; i < 4; ++i)
#pragma unroll
      for (int j = 0; j < 4; ++j)
        *reinterpret_cast<f32x4*>(&red[(t << 6) + (i * 4 + j) * 4]) = acc[i][j];
  }
  __syncthreads();
  if (!grp) {
    const int crow = (l >> 4) * 4;
    const int ccol = l & 15;
    float* Cf = (float*)Cv;
    unsigned short* Cb = (unsigned short*)Cv;
#pragma unroll
    for (int i = 0; i < 4; ++i) {
#pragma unroll
      for (int j = 0; j < 4; ++j) {
        const f32x4 o = *reinterpret_cast<const f32x4*>(&red[(t << 6) + (i * 4 + j) * 4]);
        const int n = bn + wc + j * 16 + ccol;
        const float bv = bias ? bias[n] : 0.f;
#pragma unroll
        for (int r = 0; r < 4; ++r) {
          const int m = bm + wr + i * 16 + crow + r;
          float v = acc[i][j][r] + o[r] + bv;
          if (act == 1) v = (v > 20.f) ? v : __logf(1.f + __expf(v));
          else if (act == 2) v = (v >= 0.f) ? v : 0.01f * v;
          if (res) v += res[(size_t)m * ldc + n];
          if (outbf) Cb[(size_t)m * ldc + n] = f2bf(v);
          else       Cf[(size_t)m * ldc + n] = v;
        }
      }
    }
  }
}

// ---------------------------------------------------------------- x_proj split-K (N=96), 2-phase (proven)
__global__ __launch_bounds__(256) void xproj_kernel(
    const unsigned short* __restrict__ A, int lda,
    const unsigned short* __restrict__ B, int ldb,
    float* __restrict__ C)
{
  __shared__ unsigned short As[2][128 * 32];
  __shared__ unsigned short Bs[2][96 * 32];
  const int t = threadIdx.x;
  const int w = t >> 6, l = t & 63;
  const int bm = blockIdx.x * 128;
  const int kbase = blockIdx.y * 128;

  f32x4 acc[2][6] = {};

  const int srow = t >> 2;
  const int sk = (t & 3) * 8;
  const unsigned short* gA0 = A + (size_t)(bm + srow) * lda + kbase + sk;
  const unsigned short* gA1 = gA0 + (size_t)64 * lda;
  const unsigned short* gB0 = B + (size_t)srow * ldb + kbase + sk;
  const unsigned short* gB1 = gB0 + (size_t)64 * ldb;

  const int fr = l & 15;
  const int kb = (l >> 4) * 8;

#define STAGEX(buf, k0) do { \
    GLDS(gA0 + (k0), &As[buf][w * 512]); \
    GLDS(gA1 + (k0), &As[buf][2048 + w * 512]); \
    GLDS(gB0 + (k0), &Bs[buf][w * 512]); \
    if (w < 2) GLDS(gB1 + (k0), &Bs[buf][2048 + w * 512]); \
  } while (0)

#define COMPUTEX(buf) do { \
    bf16x8 af[2], bfr[6]; \
    _Pragma("unroll") \
    for (int i = 0; i < 2; ++i) \
      af[i] = *reinterpret_cast<const bf16x8*>(&As[buf][(w * 32 + i * 16 + fr) * 32 + kb]); \
    _Pragma("unroll") \
    for (int j = 0; j < 6; ++j) \
      bfr[j] = *reinterpret_cast<const bf16x8*>(&Bs[buf][(j * 16 + fr) * 32 + kb]); \
    _Pragma("unroll") \
    for (int i = 0; i < 2; ++i) \
      _Pragma("unroll") \
      for (int j = 0; j < 6; ++j) \
        acc[i][j] = __builtin_amdgcn_mfma_f32_16x16x32_bf16(af[i], bfr[j], acc[i][j], 0, 0, 0); \
  } while (0)

  STAGEX(0, 0);
  DRAIN_VM();
  __syncthreads();
  int cur = 0;
  for (int s = 1; s < 4; ++s) {
    __builtin_amdgcn_sched_barrier(0);
    STAGEX(cur ^ 1, s * 32);
    __builtin_amdgcn_sched_barrier(0);
    COMPUTEX(cur);
    DRAIN_VM();
    __syncthreads();
    cur ^= 1;
  }
  COMPUTEX(cur);
#undef STAGEX
#undef COMPUTEX

  const int crow = (l >> 4) * 4;
  const int ccol = l & 15;
#pragma unroll
  for (int i = 0; i < 2; ++i)
#pragma unroll
    for (int j = 0; j < 6; ++j)
#pragma unroll
      for (int r = 0; r < 4; ++r) {
        const int m = bm + w * 32 + i * 16 + crow + r;
        const int n = j * 16 + ccol;
        atomicAdd(&C[(size_t)m * 96 + n], acc[i][j][r]);
      }
}

// ---------------------------------------------------------------- conv(k=2)+SiLU (bf16 xz)
__global__ __launch_bounds__(256) void conv_silu_kernel(
    const unsigned short* __restrict__ xz, const float* __restrict__ cw,
    const float* __restrict__ cb, float* __restrict__ xc,
    unsigned short* __restrict__ xcb)
{
  const int idx = blockIdx.x * 256 + threadIdx.x;   // over 4096*1024
  const int row = idx >> 10;
  const int d = idx & 1023;
  const int l = row & (L_SEQ - 1);
  const float cur = bf2f(xz[(size_t)row * 2048 + d]);
  const float prev = (l == 0) ? 0.f : bf2f(xz[(size_t)(row - 1) * 2048 + d]);
  const float v = prev * cw[d * 2 + 0] + cur * cw[d * 2 + 1] + cb[d];
  const float sv = v / (1.f + __expf(-v));
  xc[idx] = sv;
  xcb[idx] = f2bf(sv);
}

// ---------------------------------------------------------------- scan pass 1
__global__ __launch_bounds__(256) void scan_pass1(
    const float* __restrict__ delta, const float* __restrict__ xc,
    const float* __restrict__ xdbl, const float* __restrict__ A_log,
    float* __restrict__ hfin, float* __restrict__ pcum)
{
  const int tid = threadIdx.x;
  const int db = blockIdx.x & 3;
  const int c = (blockIdx.x >> 2) & (NCHUNK - 1);
  const int b = blockIdx.x >> 7;
  const int d = db * 256 + tid;
  __shared__ float Bsh[CH][16];
  {
    const int lr = tid >> 2, q = tid & 3;
    const float* p = xdbl + ((size_t)(b * L_SEQ + c * CH + lr) * 96) + 64 + q * 4;
    *reinterpret_cast<float4*>(&Bsh[lr][q * 4]) = *reinterpret_cast<const float4*>(p);
  }
  float a[NSTATE];
#pragma unroll
  for (int n = 0; n < NSTATE; ++n) a[n] = -__expf(A_log[d * 16 + n]);
  __syncthreads();
  float h[NSTATE], P[NSTATE];
#pragma unroll
  for (int n = 0; n < NSTATE; ++n) { h[n] = 0.f; P[n] = 1.f; }
  const size_t rowbase = (size_t)(b * L_SEQ + c * CH);
  for (int s = 0; s < CH; ++s) {
    const size_t row = rowbase + s;
    const float dl = delta[row * 1024 + d];
    const float xcv = xc[row * 1024 + d];
#pragma unroll
    for (int n = 0; n < NSTATE; ++n) {
      const float dA = __expf(dl * a[n]);
      h[n] = h[n] * dA + (dl * Bsh[s][n]) * xcv;
      P[n] *= dA;
    }
  }
  const size_t base = ((size_t)((b * NCHUNK + c) * 1024 + d)) * 16;
  float4* hp = reinterpret_cast<float4*>(hfin + base);
  float4* pp = reinterpret_cast<float4*>(pcum + base);
#pragma unroll
  for (int qq = 0; qq < 4; ++qq) {
    hp[qq] = make_float4(h[qq * 4], h[qq * 4 + 1], h[qq * 4 + 2], h[qq * 4 + 3]);
    pp[qq] = make_float4(P[qq * 4], P[qq * 4 + 1], P[qq * 4 + 2], P[qq * 4 + 3]);
  }
}

// ---------------------------------------------------------------- scan pass 2
__global__ __launch_bounds__(256) void scan_pass2(
    const float* __restrict__ hfin, const float* __restrict__ pcum,
    float* __restrict__ hstart)
{
  const int t = blockIdx.x * 256 + threadIdx.x;
  const int b = t >> 14;
  const int dn = t & 16383;
  const size_t base = (size_t)b * NCHUNK * 16384 + dn;
  float h = 0.f;
  for (int c = 0; c < NCHUNK; ++c) {
    const size_t idx = base + (size_t)c * 16384;
    hstart[idx] = h;
    h = pcum[idx] * h + hfin[idx];
  }
}

// ---------------------------------------------------------------- scan pass 3 (bf16 y out, bf16 z in)
__global__ __launch_bounds__(256) void scan_pass3(
    const float* __restrict__ delta, const float* __restrict__ xc,
    const float* __restrict__ xdbl, const float* __restrict__ A_log,
    const float* __restrict__ hstart, const float* __restrict__ Dp,
    const unsigned short* __restrict__ xz, unsigned short* __restrict__ yout)
{
  const int tid = threadIdx.x;
  const int db = blockIdx.x & 3;
  const int c = (blockIdx.x >> 2) & (NCHUNK - 1);
  const int b = blockIdx.x >> 7;
  const int d = db * 256 + tid;
  __shared__ float Bsh[CH][16];
  __shared__ float Csh[CH][16];
  {
    const int lr = tid >> 2, q = tid & 3;
    const float* p = xdbl + ((size_t)(b * L_SEQ + c * CH + lr) * 96);
    *reinterpret_cast<float4*>(&Bsh[lr][q * 4]) = *reinterpret_cast<const float4*>(p + 64 + q * 4);
    *reinterpret_cast<float4*>(&Csh[lr][q * 4]) = *reinterpret_cast<const float4*>(p + 80 + q * 4);
  }
  float a[NSTATE];
#pragma unroll
  for (int n = 0; n < NSTATE; ++n) a[n] = -__expf(A_log[d * 16 + n]);
  float h[NSTATE];
  {
    const size_t base = ((size_t)((b * NCHUNK + c) * 1024 + d)) * 16;
    const float4* hp = reinterpret_cast<const float4*>(hstart + base);
#pragma unroll
    for (int qq = 0; qq < 4; ++qq) {
      const float4 v = hp[qq];
      h[qq * 4] = v.x; h[qq * 4 + 1] = v.y; h[qq * 4 + 2] = v.z; h[qq * 4 + 3] = v.w;
    }
  }
  const float dpv = Dp[d];
  __syncthreads();
  const size_t rowbase = (size_t)(b * L_SEQ + c * CH);
  for (int s = 0; s < CH; ++s) {
    const size_t row = rowbase + s;
    const float dl = delta[row * 1024 + d];
    const float xcv = xc[row * 1024 + d];
    float y = 0.f;
#pragma unroll
    for (int n = 0; n < NSTATE; ++n) {
      const float dA = __expf(dl * a[n]);
      h[n] = h[n] * dA + (dl * Bsh[s][n]) * xcv;
      y += h[n] * Csh[s][n];
    }
    const float z = bf2f(xz[row * 2048 + 1024 + d]);
    const float sil = z / (1.f + __expf(-z));
    yout[row * 1024 + d] = f2bf((y + xcv * dpv) * sil);
  }
}

// ---------------------------------------------------------------- launch
extern "C" void kernel_launch(void* const* d_in, const int* in_sizes, int n_in,
                              void* d_out, int out_size, void* d_ws, size_t ws_size,
                              hipStream_t stream)
{
  (void)in_sizes; (void)n_in; (void)out_size; (void)ws_size;
  const float* src        = (const float*)d_in[0];
  const float* in_proj_w  = (const float*)d_in[1];
  const float* conv_w     = (const float*)d_in[2];
  const float* conv_b     = (const float*)d_in[3];
  const float* x_proj_w   = (const float*)d_in[4];
  const float* dt_proj_w  = (const float*)d_in[5];
  const float* dt_proj_b  = (const float*)d_in[6];
  const float* A_log      = (const float*)d_in[7];
  const float* Dp         = (const float*)d_in[8];
  const float* out_proj_w = (const float*)d_in[9];
  const float* mnorm_g    = (const float*)d_in[10];
  const float* mnorm_b    = (const float*)d_in[11];
  const float* n1_g       = (const float*)d_in[12];
  const float* n1_b       = (const float*)d_in[13];
  const float* n2_g       = (const float*)d_in[14];
  const float* n2_b       = (const float*)d_in[15];
  const float* n3_g       = (const float*)d_in[16];
  const float* n3_b       = (const float*)d_in[17];
  const float* ffn_w1     = (const float*)d_in[18];
  const float* ffn_w2     = (const float*)d_in[19];
  const float* fe_w       = (const float*)d_in[20];
  const float* fe_b       = (const float*)d_in[21];
  float* out = (float*)d_out;
  float* ws  = (float*)d_ws;

  // ---- workspace layout (float offsets; ranges disjoint — audited round 6) ----
  unsigned short* xzb  = (unsigned short*)ws;               // u16[0 .. 8388608)   = f[0 .. 4194304)
  unsigned short* xdblb= (unsigned short*)(ws + 4194304);   // u16 393216          = f[4194304 .. 4390912)
  unsigned short* dtwb = (unsigned short*)(ws + 4390912);   // u16 65536           = f[4390912 .. 4423680)
  float* xc    = ws + 8388608;        // f[ 8388608 .. 12582912)
  float* xdbl  = ws + 12582912;       // f[12582912 .. 12976128), slot to 13107200
  float* delta = ws + 13107200;       // f[13107200 .. 17301504)
  float* s5    = ws + 17301504;       // f[17301504 .. 21495808)
  float* src1  = ws + 21495808;       // f[21495808 .. 25690112)
  float* hfin  = ws + 25690112;       // f[25690112 .. 26738688)
  float* pcum  = ws + 26738688;       // f[26738688 .. 27787264)
  float* hst   = ws + 27787264;       // f[27787264 .. 28835840)
  unsigned short* s1b  = (unsigned short*)(ws + 28835840);  // u16 4194304 = f[.. 30932992)
  unsigned short* xcb  = (unsigned short*)(ws + 30932992);  // u16 4194304 = f[.. 33030144)
  unsigned short* yb   = (unsigned short*)(ws + 33030144);  // u16 4194304 = f[.. 35127296)
  unsigned short* f1b  = (unsigned short*)(ws + 35127296);  // u16 16777216 = f[.. 43515904)
  unsigned short* ipwb = (unsigned short*)(ws + 43515904);  // u16 2097152 = f[.. 44564480)
  unsigned short* xpwb = (unsigned short*)(ws + 44564480);  // u16 98304   = f[.. 44613632)
  unsigned short* opwb = (unsigned short*)(ws + 44613632);  // u16 1048576 = f[.. 45137920)
  unsigned short* w1b  = (unsigned short*)(ws + 45137920);  // u16 4194304 = f[.. 47235072)
  unsigned short* w2b  = (unsigned short*)(ws + 47235072);  // u16 4194304 = f[.. 49332224)
  unsigned short* fewb = (unsigned short*)(ws + 49332224);  // u16 1048576 = f[.. 49856512)

  const dim3 blk(256);
  const dim3 blk512(512);

  // 0. all weights -> bf16 (single launch; 3186688 float4s)
  cvt_all_kernel<<<12448, blk, 0, stream>>>(
      in_proj_w, x_proj_w, dt_proj_w, out_proj_w, ffn_w1, ffn_w2, fe_w,
      ipwb, xpwb, dtwb, opwb, w1b, w2b, fewb);

  // 1. x1 = LN(src; n1) -> bf16
  ln_kernel<<<NROWS, blk, 0, stream>>>(src, n1_g, n1_b, nullptr, nullptr, s1b);
  // 2. xz = x1 @ in_proj_w^T -> bf16  (4096x2048x1024, ksplit BK=32, 2 blocks/CU)
  gemm_ksplit_kernel<32><<<512, blk512, 0, stream>>>(s1b, 1024, ipwb, 1024, xzb, 2048,
                                                     nullptr, nullptr, 1024, 0, 1, 16);
  // 3. x_c = silu(conv(x_in))  -> f32 + bf16
  conv_silu_kernel<<<16384, blk, 0, stream>>>(xzb, conv_w, conv_b, xc, xcb);
  // 4. x_dbl = x_c @ x_proj_w^T  (split-K=8, atomic f32)
  hipMemsetAsync(xdbl, 0, (size_t)NROWS * 96 * sizeof(float), stream);
  xproj_kernel<<<dim3(32, 8), blk, 0, stream>>>(xcb, 1024, xpwb, 1024, xdbl);
  // 4b. xdbl -> bf16 for dt_proj
  cvt_bf16_kernel<<<384, blk, 0, stream>>>(xdbl, xdblb, 98304);
  // 5. delta = softplus(dt @ dt_proj_w^T + b)  (4096x1024x64)
  gemm_bf16_kernel<<<256, blk, 0, stream>>>(xdblb, 96, dtwb, 64, delta, 1024,
                                            dt_proj_b, nullptr, 64, 1, 0, 8);
  // 6-8. selective scan
  scan_pass1<<<256, blk, 0, stream>>>(delta, xc, xdbl, A_log, hfin, pcum);
  scan_pass2<<<128, blk, 0, stream>>>(hfin, pcum, hst);
  scan_pass3<<<256, blk, 0, stream>>>(delta, xc, xdbl, A_log, hst, Dp, xzb, yb);
  // 9. mamba_out = y @ out_proj_w^T  (4096x1024x1024, ksplit BK=64)
  gemm_ksplit_kernel<64><<<256, blk512, 0, stream>>>(yb, 1024, opwb, 1024, s5, 1024,
                                                     nullptr, nullptr, 1024, 0, 0, 8);
  // 10. src1 = src + LN(mamba_out; mnorm)
  ln_kernel<<<NROWS, blk, 0, stream>>>(s5, mnorm_g, mnorm_b, src, src1, nullptr);
  // 11. x2 = LN(src1; n2) -> bf16
  ln_kernel<<<NROWS, blk, 0, stream>>>(src1, n2_g, n2_b, nullptr, nullptr, s1b);
  // 12. f1 = leaky(x2 @ ffn_w1^T) -> bf16  (4096x4096x1024, 256x256 tile, 1 blk/CU)
  gemm256_kernel<<<256, blk512, 0, stream>>>(s1b, 1024, w1b, 1024, f1b, 4096,
                                             nullptr, nullptr, 1024, 2, 1, 16);
  // 13. src2 = src1 + f1 @ ffn_w2^T  (4096x1024x4096, ksplit BK=64)
  gemm_ksplit_kernel<64><<<256, blk512, 0, stream>>>(f1b, 4096, w2b, 4096, s5, 1024,
                                                     nullptr, src1, 4096, 0, 0, 8);
  // 14. x3 = LN(src2; n3) -> bf16
  ln_kernel<<<NROWS, blk, 0, stream>>>(s5, n3_g, n3_b, nullptr, nullptr, s1b);
  // 15. out = src2 + x3 @ fe_w^T + fe_b  (4096x1024x1024, ksplit BK=64)
  gemm_ksplit_kernel<64><<<256, blk512, 0, stream>>>(s1b, 1024, fewb, 1024, out, 1024,
                                                     fe_b, s5, 1024, 0, 0, 8);
}